// Round 1
// baseline (756.143 us; speedup 1.0000x reference)
//
#include <hip/hip_runtime.h>
#include <hip/hip_bf16.h>

#define B_   2
#define T_   2048
#define HID_ 2048
#define H_   16
#define KVH_ 4
#define D_   128
#define GQ_  (H_ / KVH_)

typedef unsigned short u16;
typedef __attribute__((ext_vector_type(8))) unsigned short us8v;
typedef __attribute__((ext_vector_type(8))) short s16x8;   // MFMA A/B frag
typedef __attribute__((ext_vector_type(4))) float f32x4;   // MFMA C/D frag

__device__ __forceinline__ float bf2f(u16 u) {
  return __uint_as_float(((unsigned)u) << 16);
}
__device__ __forceinline__ u16 f2bf(float f) {
  unsigned x = __float_as_uint(f);
  return (u16)((x + 0x7fffu + ((x >> 16) & 1u)) >> 16);  // RNE
}

// ---------------------------------------------------------------------------
// On-device dtype probe (bf16 vs fp32), per tensor — R7-proven on this
// mixed-dtype input set. Wave-uniform, deterministic, graph-capture safe.
// ---------------------------------------------------------------------------
__device__ __forceinline__ void probe2(const void* A, const void* W, int tid,
                                       bool* abf, bool* wbf) {
  __shared__ int cA, zA, cW, zW;
  if (tid == 0) { cA = 0; zA = 0; cW = 0; zW = 0; }
  __syncthreads();
  const int i = 16384 + tid;
  {
    const u16 raw = ((const u16*)A)[i];
    const float v = bf2f(raw);
    const bool bad = !(fabsf(v) <= 1e6f) ||
                     (v != 0.0f && fabsf(v) < 1e-10f);
    if (bad) atomicAdd(&cA, 1);
    if (((tid & 1) == 0) && raw == 0) atomicAdd(&zA, 1);
  }
  {
    const u16 raw = ((const u16*)W)[i];
    const float v = bf2f(raw);
    const bool bad = !(fabsf(v) <= 1e6f) ||
                     (v != 0.0f && fabsf(v) < 1e-10f);
    if (bad) atomicAdd(&cW, 1);
    if (((tid & 1) == 0) && raw == 0) atomicAdd(&zW, 1);
  }
  __syncthreads();
  *abf = (cA < 8) && (zA < 100);
  *wbf = (cW < 8) && (zW < 100);
}

// ---------------------------------------------------------------------------
// Transpose W[K][N] (bf16 OR fp32, probed) -> WT[N][K] bf16. Runs once per
// weight; makes GEMM B-staging k-contiguous (required by MFMA B-fragment).
// ---------------------------------------------------------------------------
__global__ __launch_bounds__(256) void transp_k(const void* __restrict__ Wv_,
                                                u16* __restrict__ WT,
                                                int K, int N) {
  const int tid = threadIdx.x;
  bool wbf, dummy;
  probe2(Wv_, Wv_, tid, &wbf, &dummy);

  __shared__ float tile[64][65];
  const int kb = blockIdx.y * 64;
  const int nb = blockIdx.x * 64;

  for (int it = tid; it < 512; it += 256) {
    const int r = it >> 3;            // k-row 0..63
    const int g = it & 7;             // n-granule
    const size_t off = (size_t)(kb + r) * N + nb + g * 8;
    float f[8];
    if (wbf) {
      const us8v t8 = *(const us8v*)((const u16*)Wv_ + off);
#pragma unroll
      for (int e = 0; e < 8; ++e) f[e] = bf2f(t8[e]);
    } else {
      const float4 f0 = *(const float4*)((const float*)Wv_ + off);
      const float4 f1 = *(const float4*)((const float*)Wv_ + off + 4);
      f[0] = f0.x; f[1] = f0.y; f[2] = f0.z; f[3] = f0.w;
      f[4] = f1.x; f[5] = f1.y; f[6] = f1.z; f[7] = f1.w;
    }
#pragma unroll
    for (int e = 0; e < 8; ++e) tile[r][g * 8 + e] = f[e];
  }
  __syncthreads();
  for (int it = tid; it < 512; it += 256) {
    const int n = it >> 3;            // 0..63
    const int g = it & 7;             // k-granule
    us8v tmp;
#pragma unroll
    for (int e = 0; e < 8; ++e) tmp[e] = f2bf(tile[g * 8 + e][n]);
    *(us8v*)&WT[(size_t)(nb + n) * K + kb + g * 8] = tmp;
  }
}

// ---------------------------------------------------------------------------
// MFMA GEMM: C[M,N] = A[M,K] @ W[K,N], W given pre-transposed (WT[N][K],
// bf16). A bf16 OR fp32 (probed). 128x128 tile, 4 waves (2x2), each wave
// 4x4 tiles of v_mfma_f32_16x16x32_bf16, BK=32.
// OMODE: 0 = fp32 out, 1 = bf16 out, 2 = bf16 out TRANSPOSED into
//        [b][n][t] layout (V^T for attention's PV B-fragments).
// ---------------------------------------------------------------------------
template <int OMODE>
__global__ __launch_bounds__(256) void gemm_mfma(const void* __restrict__ Av,
                                                 const u16* __restrict__ WT,
                                                 void* __restrict__ Cv,
                                                 int M, int N, int K) {
  const int tid = threadIdx.x;
  bool abf, dummy;
  probe2(Av, Av, tid, &abf, &dummy);

  __shared__ __align__(16) u16 Alds[128 * 40];
  __shared__ __align__(16) u16 Blds[128 * 40];

  const int m0 = blockIdx.y * 128;
  const int n0 = blockIdx.x * 128;
  const int wave = tid >> 6;
  const int lane = tid & 63;
  const int wm = (wave >> 1) * 64;
  const int wn = (wave & 1) * 64;
  const int lrow = lane & 15;
  const int lq = lane >> 4;

  f32x4 acc[4][4] = {};

  for (int k0 = 0; k0 < K; k0 += 32) {
    for (int it = tid; it < 512; it += 256) {
      const int r = it >> 2;
      const int g = it & 3;
      const size_t off = (size_t)(m0 + r) * K + k0 + g * 8;
      us8v tmp;
      if (abf) {
        tmp = *(const us8v*)((const u16*)Av + off);
      } else {
        const float4 f0 = *(const float4*)((const float*)Av + off);
        const float4 f1 = *(const float4*)((const float*)Av + off + 4);
        tmp[0] = f2bf(f0.x); tmp[1] = f2bf(f0.y);
        tmp[2] = f2bf(f0.z); tmp[3] = f2bf(f0.w);
        tmp[4] = f2bf(f1.x); tmp[5] = f2bf(f1.y);
        tmp[6] = f2bf(f1.z); tmp[7] = f2bf(f1.w);
      }
      *(us8v*)&Alds[r * 40 + g * 8] = tmp;
    }
    for (int it = tid; it < 512; it += 256) {
      const int n = it >> 2;
      const int g = it & 3;
      *(us8v*)&Blds[n * 40 + g * 8] =
          *(const us8v*)&WT[(size_t)(n0 + n) * K + k0 + g * 8];
    }
    __syncthreads();

    s16x8 af[4], bfr[4];
#pragma unroll
    for (int mi = 0; mi < 4; ++mi)
      af[mi] = *(const s16x8*)&Alds[(wm + 16 * mi + lrow) * 40 + lq * 8];
#pragma unroll
    for (int ni = 0; ni < 4; ++ni)
      bfr[ni] = *(const s16x8*)&Blds[(wn + 16 * ni + lrow) * 40 + lq * 8];
#pragma unroll
    for (int mi = 0; mi < 4; ++mi)
#pragma unroll
      for (int ni = 0; ni < 4; ++ni)
        acc[mi][ni] = __builtin_amdgcn_mfma_f32_16x16x32_bf16(
            af[mi], bfr[ni], acc[mi][ni], 0, 0, 0);
    __syncthreads();
  }

  // epilogue: D col=lane&15, row=quad*4+reg
#pragma unroll
  for (int mi = 0; mi < 4; ++mi) {
#pragma unroll
    for (int ni = 0; ni < 4; ++ni) {
      const int row0 = m0 + wm + 16 * mi + lq * 4;
      const int col = n0 + wn + 16 * ni + lrow;
#pragma unroll
      for (int r = 0; r < 4; ++r) {
        const int row = row0 + r;
        if (OMODE == 0) {
          ((float*)Cv)[(size_t)row * N + col] = acc[mi][ni][r];
        } else if (OMODE == 1) {
          ((u16*)Cv)[(size_t)row * N + col] = f2bf(acc[mi][ni][r]);
        } else {
          // transposed: row = b*T_ + t, out[(b*N + col)*T_ + t]
          const int bb = row >> 11;          // T_ == 2048
          const int tt = row & (T_ - 1);
          ((u16*)Cv)[((size_t)bb * N + col) * T_ + tt] = f2bf(acc[mi][ni][r]);
        }
      }
    }
  }
}

// ---------------------------------------------------------------------------
// RoPE (rotate-half), in place on a BF16 (B, T, NH, D) workspace tensor.
// ---------------------------------------------------------------------------
__global__ __launch_bounds__(256) void rope_bf(u16* __restrict__ t,
                                               const void* __restrict__ cosT,
                                               const void* __restrict__ sinT,
                                               int NH, int total) {
  const int tid = threadIdx.x;
  bool cbf, sbf;
  probe2(cosT, sinT, tid, &cbf, &sbf);

  const int idx = blockIdx.x * blockDim.x + tid;
  if (idx >= total) return;
  const int d = idx & 63;
  const int rest = idx >> 6;
  const int tt = (rest / NH) % T_;
  const size_t base = (size_t)rest * D_;
  const int ci = tt * D_ + d;
  float c1, s1, c2, s2;
  if (cbf) {
    c1 = bf2f(((const u16*)cosT)[ci]);
    c2 = bf2f(((const u16*)cosT)[ci + 64]);
  } else {
    c1 = ((const float*)cosT)[ci];
    c2 = ((const float*)cosT)[ci + 64];
  }
  if (sbf) {
    s1 = bf2f(((const u16*)sinT)[ci]);
    s2 = bf2f(((const u16*)sinT)[ci + 64]);
  } else {
    s1 = ((const float*)sinT)[ci];
    s2 = ((const float*)sinT)[ci + 64];
  }
  const float x1 = bf2f(t[base + d]);
  const float x2 = bf2f(t[base + d + 64]);
  t[base + d] = f2bf(x1 * c1 - x2 * s1);
  t[base + d + 64] = f2bf(x2 * c2 + x1 * s2);
}

// ---------------------------------------------------------------------------
// Causal GQA flash attention, MFMA version (NEW this round).
// Block: 64 q-rows of one (b,h); 4 waves, wave w owns q-rows [w*16,w*16+16).
// KV tiles of 64. v_mfma_f32_16x16x32_bf16 throughout.
// Fragment layouts (m89/m91-verified, same as gemm_mfma above):
//   A: lane holds A[m=lane&15][k=quad*8+j]   (8 contiguous k)
//   B: lane holds B[n=lane&15][k=quad*8+j]   (8 contiguous k)
//   D: col=lane&15, row=quad*4+reg
// QK^T: A=Q rows (global, reg-resident), B=K rows (LDS, XOR-swizzled).
// Softmax: D-layout is 4 q-rows/lane x 4 k-tiles -> in-register online
// softmax; row-reduce = fmax/sum + shfl_xor(1,2,4,8) within 16-lane group.
// m/l state in registers (wave-private rows, no LDS state, no extra barrier).
// PV: P round-trips wave-private LDS (bf16) to A-layout; V comes from a
// GLOBALLY pre-transposed vT ([b][kvh][d][t], written by the V-proj GEMM)
// so B-fragments are contiguous ds_read_b128 (XOR-swizzled).
// ---------------------------------------------------------------------------
__global__ __launch_bounds__(256, 2) void attn_mfma(
    const u16* __restrict__ q, const u16* __restrict__ k,
    const u16* __restrict__ vT, u16* __restrict__ o) {
  const float scale = 0.08838834764831845f;  // 1/sqrt(128)
  const int tid = threadIdx.x;
  const int qt = blockIdx.x;
  const int bh = blockIdx.y;
  const int b = bh >> 4;
  const int h = bh & 15;
  const int kvh = h >> 2;
  const int q0 = qt * 64;

  __shared__ __align__(16) u16 Ks[64 * 128];   // [krow][d], granule-XOR
  __shared__ __align__(16) u16 Vt[128 * 64];   // [d][k],   granule-XOR
  __shared__ __align__(16) u16 Pl[64 * 64];    // [q][k] bf16, granule-XOR

  const int wave = tid >> 6;
  const int lane = tid & 63;
  const int l15 = lane & 15;
  const int quad = lane >> 4;
  const int wq = wave * 16;

  // Q fragments, reg-resident for the whole block: A[m=l15][d=st*32+quad*8+j]
  s16x8 qf[4];
  {
    const size_t qrow = ((size_t)(b * T_ + q0 + wq + l15) * H_ + h) * D_;
#pragma unroll
    for (int st = 0; st < 4; ++st)
      qf[st] = *(const s16x8*)&q[qrow + st * 32 + quad * 8];
  }

  f32x4 acc_o[8] = {};          // 8 d-tiles of 16; rows = quad*4+r
  float m_r[4], l_r[4];
#pragma unroll
  for (int r = 0; r < 4; ++r) { m_r[r] = -1.0e30f; l_r[r] = 0.0f; }

  const int nkt = qt + 1;
  for (int kt = 0; kt < nkt; ++kt) {
    const int k0 = kt * 64;
    __syncthreads();  // previous tile's LDS reads done
    // ---- stage K tile: 64 rows x 128 d ----
    for (int it = tid; it < 1024; it += 256) {
      const int r = it >> 4;
      const int g = it & 15;
      *(us8v*)&Ks[r * 128 + ((g ^ (r & 7)) << 3)] =
          *(const us8v*)&k[((size_t)(b * T_ + k0 + r) * KVH_ + kvh) * D_ +
                           g * 8];
    }
    // ---- stage V^T tile: 128 d-rows x 64 k (vectorized; vT pre-transposed)
    for (int it = tid; it < 1024; it += 256) {
      const int r = it >> 3;    // d-row 0..127
      const int g = it & 7;     // k-granule
      *(us8v*)&Vt[r * 64 + ((g ^ (r & 7)) << 3)] =
          *(const us8v*)&vT[((size_t)(b * KVH_ + kvh) * D_ + r) * T_ + k0 +
                            g * 8];
    }
    __syncthreads();

    // ---- QK^T: S[16q x 64k] per wave ----
    f32x4 accs[4] = {};
#pragma unroll
    for (int st = 0; st < 4; ++st) {
      const int g = st * 4 + quad;
#pragma unroll
      for (int nt = 0; nt < 4; ++nt) {
        const int row = nt * 16 + l15;
        const s16x8 kf =
            *(const s16x8*)&Ks[row * 128 + ((g ^ (row & 7)) << 3)];
        accs[nt] = __builtin_amdgcn_mfma_f32_16x16x32_bf16(qf[st], kf,
                                                           accs[nt], 0, 0, 0);
      }
    }

    // ---- mask + in-register online softmax ----
    const bool lastt = (kt == qt);
    float pmax[4];
#pragma unroll
    for (int r = 0; r < 4; ++r) pmax[r] = -1.0e30f;
#pragma unroll
    for (int nt = 0; nt < 4; ++nt) {
#pragma unroll
      for (int r = 0; r < 4; ++r) {
        float s = accs[nt][r] * scale;
        if (lastt && (wq + quad * 4 + r) < (nt * 16 + l15)) s = -1.0e30f;
        accs[nt][r] = s;
        pmax[r] = fmaxf(pmax[r], s);
      }
    }
#pragma unroll
    for (int r = 0; r < 4; ++r) {
      pmax[r] = fmaxf(pmax[r], __shfl_xor(pmax[r], 1));
      pmax[r] = fmaxf(pmax[r], __shfl_xor(pmax[r], 2));
      pmax[r] = fmaxf(pmax[r], __shfl_xor(pmax[r], 4));
      pmax[r] = fmaxf(pmax[r], __shfl_xor(pmax[r], 8));
    }
    float al[4], rsum[4];
#pragma unroll
    for (int r = 0; r < 4; ++r) {
      const float mnew = fmaxf(m_r[r], pmax[r]);
      al[r] = __expf(m_r[r] - mnew);   // 0 on first tile (m=-1e30)
      m_r[r] = mnew;
      rsum[r] = 0.0f;
    }
#pragma unroll
    for (int nt = 0; nt < 4; ++nt)
#pragma unroll
      for (int r = 0; r < 4; ++r) {
        const float p = __expf(accs[nt][r] - m_r[r]);
        accs[nt][r] = p;
        rsum[r] += p;
      }
#pragma unroll
    for (int r = 0; r < 4; ++r) {
      rsum[r] += __shfl_xor(rsum[r], 1);
      rsum[r] += __shfl_xor(rsum[r], 2);
      rsum[r] += __shfl_xor(rsum[r], 4);
      rsum[r] += __shfl_xor(rsum[r], 8);
      l_r[r] = l_r[r] * al[r] + rsum[r];
    }
    // rescale O accumulator
#pragma unroll
    for (int nt2 = 0; nt2 < 8; ++nt2)
#pragma unroll
      for (int r = 0; r < 4; ++r) acc_o[nt2][r] *= al[r];

    // ---- P -> wave-private LDS (bf16), D-layout -> A-layout ----
#pragma unroll
    for (int nt = 0; nt < 4; ++nt)
#pragma unroll
      for (int r = 0; r < 4; ++r) {
        const int qq = wq + quad * 4 + r;
        const int c = nt * 16 + l15;
        Pl[qq * 64 + (((c >> 3) ^ (qq & 7)) << 3) + (c & 7)] =
            f2bf(accs[nt][r]);
      }
    // (wave-private region: compiler's lgkmcnt orders write->read; no barrier)

    // ---- PV: O[16q x 128d] += P[16x64] @ V[64x128] ----
    s16x8 pa[2];
#pragma unroll
    for (int ks = 0; ks < 2; ++ks) {
      const int row = wq + l15;
      const int g = ks * 4 + quad;
      pa[ks] = *(const s16x8*)&Pl[row * 64 + ((g ^ (row & 7)) << 3)];
    }
#pragma unroll
    for (int ks = 0; ks < 2; ++ks) {
      const int g = ks * 4 + quad;
#pragma unroll
      for (int nt2 = 0; nt2 < 8; ++nt2) {
        const int row = nt2 * 16 + l15;
        const s16x8 vf =
            *(const s16x8*)&Vt[row * 64 + ((g ^ (row & 7)) << 3)];
        acc_o[nt2] = __builtin_amdgcn_mfma_f32_16x16x32_bf16(pa[ks], vf,
                                                             acc_o[nt2],
                                                             0, 0, 0);
      }
    }
  }

  // ---- epilogue: normalize + store (D col=l15, row=quad*4+r) ----
#pragma unroll
  for (int r = 0; r < 4; ++r) {
    const float linv = 1.0f / l_r[r];
    const size_t orow =
        ((size_t)(b * T_ + q0 + wq + quad * 4 + r) * H_ + h) * D_;
#pragma unroll
    for (int nt2 = 0; nt2 < 8; ++nt2)
      o[orow + nt2 * 16 + l15] = f2bf(acc_o[nt2][r] * linv);
  }
}

// Fallback: zero d_out (fp32) so an undersized workspace fails cleanly.
__global__ void zero_out_k(float* __restrict__ out, int n) {
  const int i = blockIdx.x * blockDim.x + threadIdx.x;
  if (i < n) out[i] = 0.0f;
}

// ---------------------------------------------------------------------------
extern "C" void kernel_launch(void* const* d_in, const int* in_sizes, int n_in,
                              void* d_out, int out_size, void* d_ws,
                              size_t ws_size, hipStream_t stream) {
  const void* x    = d_in[0];
  const void* cosT = d_in[1];
  const void* sinT = d_in[2];
  const void* Wq   = d_in[3];
  const void* Wk   = d_in[4];
  const void* Wv   = d_in[5];
  const void* Wo   = d_in[6];
  float* out = (float*)d_out;

  // Workspace (bf16 elems): qbuf QN | kbuf KN | vbufT KN | obuf QN |
  //   WqT 4194304 | WkT 1048576 | WvT 1048576 | WoT 4194304  = 60 MiB.
  const size_t QN = (size_t)B_ * T_ * H_ * D_;     // 8388608
  const size_t KN = (size_t)B_ * T_ * KVH_ * D_;   // 2097152
  const size_t WQT = (size_t)HID_ * (H_ * D_);     // 4194304
  const size_t WKT = (size_t)HID_ * (KVH_ * D_);   // 1048576
  const size_t need = (2 * QN + 2 * KN + 2 * WQT + 2 * WKT) * sizeof(u16);
  if (ws_size < need) {
    zero_out_k<<<(out_size + 255) / 256, 256, 0, stream>>>(out, out_size);
    return;
  }

  u16* qbuf  = (u16*)d_ws;
  u16* kbuf  = qbuf + QN;
  u16* vbufT = kbuf + KN;    // V^T: [b][kvh][d][t]
  u16* obuf  = vbufT + KN;
  u16* WqT   = obuf + QN;
  u16* WkT   = WqT + WQT;
  u16* WvT   = WkT + WKT;
  u16* WoT   = WvT + WKT;

  const int M = B_ * T_;  // 4096
  dim3 blk(256);

  // One-time weight transposes (W[K][N] -> WT[N][K] bf16).
  transp_k<<<dim3((H_ * D_) / 64, HID_ / 64), blk, 0, stream>>>(
      Wq, WqT, HID_, H_ * D_);
  transp_k<<<dim3((KVH_ * D_) / 64, HID_ / 64), blk, 0, stream>>>(
      Wk, WkT, HID_, KVH_ * D_);
  transp_k<<<dim3((KVH_ * D_) / 64, HID_ / 64), blk, 0, stream>>>(
      Wv, WvT, HID_, KVH_ * D_);
  transp_k<<<dim3(HID_ / 64, (H_ * D_) / 64), blk, 0, stream>>>(
      Wo, WoT, H_ * D_, HID_);

  // Projections (MFMA). V writes its output TRANSPOSED ([b][kvh][d][t]).
  gemm_mfma<1><<<dim3((H_ * D_) / 128, M / 128), blk, 0, stream>>>(
      x, WqT, qbuf, M, H_ * D_, HID_);
  gemm_mfma<1><<<dim3((KVH_ * D_) / 128, M / 128), blk, 0, stream>>>(
      x, WkT, kbuf, M, KVH_ * D_, HID_);
  gemm_mfma<2><<<dim3((KVH_ * D_) / 128, M / 128), blk, 0, stream>>>(
      x, WvT, vbufT, M, KVH_ * D_, HID_);

  const int totq = B_ * T_ * H_ * (D_ / 2);   // 4194304
  rope_bf<<<totq / 256, blk, 0, stream>>>(qbuf, cosT, sinT, H_, totq);
  const int totk = B_ * T_ * KVH_ * (D_ / 2); // 1048576
  rope_bf<<<totk / 256, blk, 0, stream>>>(kbuf, cosT, sinT, KVH_, totk);

  // MFMA flash attention.
  attn_mfma<<<dim3(T_ / 64, B_ * H_), blk, 0, stream>>>(
      qbuf, kbuf, vbufT, obuf);

  // Output projection (MFMA, fp32 out).
  gemm_mfma<0><<<dim3(HID_ / 128, M / 128), blk, 0, stream>>>(
      obuf, WoT, out, M, HID_, H_ * D_);
}

// Round 3
// 427.257 us; speedup vs baseline: 1.7698x; 1.7698x over previous
//
#include <hip/hip_runtime.h>
#include <hip/hip_bf16.h>

#define B_   2
#define T_   2048
#define HID_ 2048
#define H_   16
#define KVH_ 4
#define D_   128
#define GQ_  (H_ / KVH_)

#define QN_  8388608   // B*T*H*D
#define KN_  2097152   // B*T*KVH*D

typedef unsigned short u16;
typedef __attribute__((ext_vector_type(8))) unsigned short us8v;
typedef __attribute__((ext_vector_type(8))) short s16x8;   // MFMA A/B frag
typedef __attribute__((ext_vector_type(4))) float f32x4;   // MFMA C/D frag

__device__ __forceinline__ float bf2f(u16 u) {
  return __uint_as_float(((unsigned)u) << 16);
}
__device__ __forceinline__ u16 f2bf(float f) {
  unsigned x = __float_as_uint(f);
  return (u16)((x + 0x7fffu + ((x >> 16) & 1u)) >> 16);  // RNE
}

// global(16B per lane) -> LDS direct, wave-uniform dst base + lane*16.
__device__ __forceinline__ void gl2lds(const void* gp, void* lp) {
  __builtin_amdgcn_global_load_lds(
      (const __attribute__((address_space(1))) unsigned int*)gp,
      (__attribute__((address_space(3))) unsigned int*)lp, 16, 0, 0);
}

// ---------------------------------------------------------------------------
// On-device dtype probe (bf16 vs fp32), per tensor — R7-proven on this
// mixed-dtype input set. Wave-uniform, deterministic, graph-capture safe.
// ---------------------------------------------------------------------------
__device__ __forceinline__ void probe2(const void* A, const void* W, int tid,
                                       bool* abf, bool* wbf) {
  __shared__ int cA, zA, cW, zW;
  if (tid == 0) { cA = 0; zA = 0; cW = 0; zW = 0; }
  __syncthreads();
  const int i = 16384 + tid;
  {
    const u16 raw = ((const u16*)A)[i];
    const float v = bf2f(raw);
    const bool bad = !(fabsf(v) <= 1e6f) ||
                     (v != 0.0f && fabsf(v) < 1e-10f);
    if (bad) atomicAdd(&cA, 1);
    if (((tid & 1) == 0) && raw == 0) atomicAdd(&zA, 1);
  }
  {
    const u16 raw = ((const u16*)W)[i];
    const float v = bf2f(raw);
    const bool bad = !(fabsf(v) <= 1e6f) ||
                     (v != 0.0f && fabsf(v) < 1e-10f);
    if (bad) atomicAdd(&cW, 1);
    if (((tid & 1) == 0) && raw == 0) atomicAdd(&zW, 1);
  }
  __syncthreads();
  *abf = (cA < 8) && (zA < 100);
  *wbf = (cW < 8) && (zW < 100);
}

// ---------------------------------------------------------------------------
// Transpose W[K][N] (bf16 OR fp32, probed) -> WT[N][K] bf16. Runs once per
// weight; makes GEMM B-staging k-contiguous (required by MFMA B-fragment).
// ---------------------------------------------------------------------------
__global__ __launch_bounds__(256) void transp_k(const void* __restrict__ Wv_,
                                                u16* __restrict__ WT,
                                                int K, int N) {
  const int tid = threadIdx.x;
  bool wbf, dummy;
  probe2(Wv_, Wv_, tid, &wbf, &dummy);

  __shared__ float tile[64][65];
  const int kb = blockIdx.y * 64;
  const int nb = blockIdx.x * 64;

  for (int it = tid; it < 512; it += 256) {
    const int r = it >> 3;            // k-row 0..63
    const int g = it & 7;             // n-granule
    const size_t off = (size_t)(kb + r) * N + nb + g * 8;
    float f[8];
    if (wbf) {
      const us8v t8 = *(const us8v*)((const u16*)Wv_ + off);
#pragma unroll
      for (int e = 0; e < 8; ++e) f[e] = bf2f(t8[e]);
    } else {
      const float4 f0 = *(const float4*)((const float*)Wv_ + off);
      const float4 f1 = *(const float4*)((const float*)Wv_ + off + 4);
      f[0] = f0.x; f[1] = f0.y; f[2] = f0.z; f[3] = f0.w;
      f[4] = f1.x; f[5] = f1.y; f[6] = f1.z; f[7] = f1.w;
    }
#pragma unroll
    for (int e = 0; e < 8; ++e) tile[r][g * 8 + e] = f[e];
  }
  __syncthreads();
  for (int it = tid; it < 512; it += 256) {
    const int n = it >> 3;            // 0..63
    const int g = it & 7;             // k-granule
    us8v tmp;
#pragma unroll
    for (int e = 0; e < 8; ++e) tmp[e] = f2bf(tile[g * 8 + e][n]);
    *(us8v*)&WT[(size_t)(nb + n) * K + kb + g * 8] = tmp;
  }
}

// ---------------------------------------------------------------------------
// MFMA GEMM: C[M,N] = A[M,K] @ W[K,N], W pre-transposed (WT[N][K], bf16).
// A bf16 OR fp32 (probed). 128x128 tile, 4 waves (2x2), 4x4
// v_mfma_f32_16x16x32_bf16 per wave, BK=32.
// LDS: linear [128][32] u16, staged via global_load_lds w=16 with the
// granule XOR-swizzle g^((r>>1)&3) FOLDED INTO THE GLOBAL SOURCE (m173,
// rule #21). Fragment reads apply the same involution: bank-quad slot
// (16*(r&1)+4*pos) mod 32 then covers all 8 slots evenly -> conflict-free
// ds_read_b128 (the R2 linear layout was an 8-way conflict).
// OMODE: 0 = fp32 out row-major.
//        3 = fused QKV epilogue: col<2048 -> qbuf[row*2048+col] bf16;
//            col<2560 -> kbuf[row*512+(col-2048)];
//            else     -> vT[((b*KVH+kvh)*D+d)*T+t]  (V pre-transposed for
//            attention's PV B-fragments). Cv = qbuf base; kbuf/vT at fixed
//            offsets QN_/QN_+KN_.
// ---------------------------------------------------------------------------
template <int OMODE>
__global__ __launch_bounds__(256) void gemm_mfma(const void* __restrict__ Av,
                                                 const u16* __restrict__ WT,
                                                 void* __restrict__ Cv,
                                                 int M, int N, int K) {
  const int tid = threadIdx.x;
  bool abf, dummy;
  probe2(Av, Av, tid, &abf, &dummy);

  __shared__ __align__(16) u16 Alds[128 * 32];
  __shared__ __align__(16) u16 Blds[128 * 32];

  const int m0 = blockIdx.y * 128;
  const int n0 = blockIdx.x * 128;
  const int wave = tid >> 6;
  const int lane = tid & 63;
  const int wm = (wave >> 1) * 64;
  const int wn = (wave & 1) * 64;
  const int lrow = lane & 15;
  const int lq = lane >> 4;

  f32x4 acc[4][4] = {};

  for (int k0 = 0; k0 < K; k0 += 32) {
    __syncthreads();  // previous iteration's LDS reads complete
    if (abf) {
#pragma unroll
      for (int p = 0; p < 2; ++p) {
        const int it = tid + p * 256;
        const int r = it >> 2, g = it & 3;
        const int gs = g ^ ((r >> 1) & 3);   // source pre-swizzle
        gl2lds((const u16*)Av + (size_t)(m0 + r) * K + k0 + gs * 8,
               &Alds[((tid & ~63) + p * 256) * 8]);
      }
    } else {
#pragma unroll
      for (int p = 0; p < 2; ++p) {
        const int it = tid + p * 256;
        const int r = it >> 2, g = it & 3;
        const int gs = g ^ ((r >> 1) & 3);
        const size_t off = (size_t)(m0 + r) * K + k0 + gs * 8;
        const float4 f0 = *(const float4*)((const float*)Av + off);
        const float4 f1 = *(const float4*)((const float*)Av + off + 4);
        us8v tmp;
        tmp[0] = f2bf(f0.x); tmp[1] = f2bf(f0.y);
        tmp[2] = f2bf(f0.z); tmp[3] = f2bf(f0.w);
        tmp[4] = f2bf(f1.x); tmp[5] = f2bf(f1.y);
        tmp[6] = f2bf(f1.z); tmp[7] = f2bf(f1.w);
        *(us8v*)&Alds[r * 32 + g * 8] = tmp;
      }
    }
#pragma unroll
    for (int p = 0; p < 2; ++p) {
      const int it = tid + p * 256;
      const int n = it >> 2, g = it & 3;
      const int gs = g ^ ((n >> 1) & 3);
      gl2lds(WT + (size_t)(n0 + n) * K + k0 + gs * 8,
             &Blds[((tid & ~63) + p * 256) * 8]);
    }
    __syncthreads();  // compiler drains vmcnt+lgkmcnt here

    s16x8 af[4], bfr[4];
#pragma unroll
    for (int mi = 0; mi < 4; ++mi) {
      const int row = wm + 16 * mi + lrow;
      af[mi] = *(const s16x8*)&Alds[row * 32 + ((lq ^ ((row >> 1) & 3)) * 8)];
    }
#pragma unroll
    for (int ni = 0; ni < 4; ++ni) {
      const int row = wn + 16 * ni + lrow;
      bfr[ni] = *(const s16x8*)&Blds[row * 32 + ((lq ^ ((row >> 1) & 3)) * 8)];
    }
#pragma unroll
    for (int mi = 0; mi < 4; ++mi)
#pragma unroll
      for (int ni = 0; ni < 4; ++ni)
        acc[mi][ni] = __builtin_amdgcn_mfma_f32_16x16x32_bf16(
            af[mi], bfr[ni], acc[mi][ni], 0, 0, 0);
  }

  // epilogue: D col=lane&15, row=quad*4+reg
#pragma unroll
  for (int mi = 0; mi < 4; ++mi) {
#pragma unroll
    for (int ni = 0; ni < 4; ++ni) {
      const int row0 = m0 + wm + 16 * mi + lq * 4;
      const int col = n0 + wn + 16 * ni + lrow;
#pragma unroll
      for (int r = 0; r < 4; ++r) {
        const int row = row0 + r;
        if (OMODE == 0) {
          ((float*)Cv)[(size_t)row * N + col] = acc[mi][ni][r];
        } else {
          const u16 val = f2bf(acc[mi][ni][r]);
          if (col < 2048) {
            ((u16*)Cv)[(size_t)row * 2048 + col] = val;           // qbuf
          } else if (col < 2560) {
            ((u16*)Cv)[QN_ + (size_t)row * 512 + (col - 2048)] = val;  // kbuf
          } else {
            const int c = col - 2560;          // 0..511
            const int kvh = c >> 7;
            const int d = c & 127;
            const int bb = row >> 11;          // T_ == 2048
            const int tt = row & (T_ - 1);
            ((u16*)Cv)[QN_ + KN_ +
                       ((size_t)(bb * KVH_ + kvh) * D_ + d) * T_ + tt] = val;
          }
        }
      }
    }
  }
}

// ---------------------------------------------------------------------------
// RoPE (rotate-half), in place on a BF16 (B, T, NH, D) workspace tensor.
// ---------------------------------------------------------------------------
__global__ __launch_bounds__(256) void rope_bf(u16* __restrict__ t,
                                               const void* __restrict__ cosT,
                                               const void* __restrict__ sinT,
                                               int NH, int total) {
  const int tid = threadIdx.x;
  bool cbf, sbf;
  probe2(cosT, sinT, tid, &cbf, &sbf);

  const int idx = blockIdx.x * blockDim.x + tid;
  if (idx >= total) return;
  const int d = idx & 63;
  const int rest = idx >> 6;
  const int tt = (rest / NH) % T_;
  const size_t base = (size_t)rest * D_;
  const int ci = tt * D_ + d;
  float c1, s1, c2, s2;
  if (cbf) {
    c1 = bf2f(((const u16*)cosT)[ci]);
    c2 = bf2f(((const u16*)cosT)[ci + 64]);
  } else {
    c1 = ((const float*)cosT)[ci];
    c2 = ((const float*)cosT)[ci + 64];
  }
  if (sbf) {
    s1 = bf2f(((const u16*)sinT)[ci]);
    s2 = bf2f(((const u16*)sinT)[ci + 64]);
  } else {
    s1 = ((const float*)sinT)[ci];
    s2 = ((const float*)sinT)[ci + 64];
  }
  const float x1 = bf2f(t[base + d]);
  const float x2 = bf2f(t[base + d + 64]);
  t[base + d] = f2bf(x1 * c1 - x2 * s1);
  t[base + d + 64] = f2bf(x2 * c2 + x1 * s2);
}

// ---------------------------------------------------------------------------
// Causal GQA flash attention, MFMA v2:
//  - QBLK=128 (4 waves x 32 q-rows, 2 A-frags/wave): every K/V LDS fragment
//    feeds 2 MFMAs (arithmetic intensity doubled vs R1).
//  - K/V staged via global_load_lds w=16 with PRE-SWIZZLED global source
//    (LDS linear, XOR granule swizzle folded into the source address).
//  - Double-buffered K/V (2x32KB) + Pl 16KB = 80KB LDS, 2 blocks/CU,
//    grid 512 = fully resident. ONE barrier per KV tile: stage(t+1,buf^1)
//    issues at top of compute(t); barrier drains vmcnt.
//  - Heavy-first dispatch: qt reversed on blockIdx.y.
//  - Per-wave early-out for fully-masked tiles.
// ---------------------------------------------------------------------------
#define ATT_STAGE(bi, ktile)                                                  \
  do {                                                                        \
    const int _k0 = (ktile) * 64;                                             \
    u16* _bk = &SM[(bi) * 16384];                                             \
    _Pragma("unroll") for (int _p = 0; _p < 4; ++_p) {                        \
      const int _it = tid + _p * 256;                                         \
      const int _r = _it >> 4, _s = _it & 15;                                 \
      gl2lds(kp + (size_t)(_k0 + _r) * (KVH_ * D_) + ((_s ^ (_r & 7)) * 8),   \
             &_bk[((tid & ~63) + _p * 256) * 8]);                             \
    }                                                                         \
    _Pragma("unroll") for (int _p = 0; _p < 4; ++_p) {                        \
      const int _it = tid + _p * 256;                                         \
      const int _r = _it >> 3, _s = _it & 7;                                  \
      gl2lds(vp + (size_t)_r * T_ + _k0 + ((_s ^ (_r & 7)) * 8),              \
             &_bk[8192 + ((tid & ~63) + _p * 256) * 8]);                      \
    }                                                                         \
  } while (0)

__global__ __launch_bounds__(256, 2) void attn_mfma(
    const u16* __restrict__ q, const u16* __restrict__ k,
    const u16* __restrict__ vT, u16* __restrict__ o) {
  const float scale = 0.08838834764831845f;  // 1/sqrt(128)
  const int tid = threadIdx.x;
  const int qt = (int)gridDim.y - 1 - (int)blockIdx.y;  // heavy first
  const int bh = blockIdx.x;
  const int b = bh >> 4;
  const int h = bh & 15;
  const int kvh = h >> 2;
  const int q0 = qt * 128;

  __shared__ __align__(16) u16 SM[2 * 16384];  // dbuf {Ks 64x128, Vt 128x64}
  __shared__ __align__(16) u16 Pl[128 * 64];   // P (bf16), granule-XOR

  const int wave = tid >> 6;
  const int lane = tid & 63;
  const int l15 = lane & 15;
  const int quad = lane >> 4;
  const int wq = wave * 32;

  const u16* kp = k + ((size_t)b * T_ * KVH_ + kvh) * D_;
  const u16* vp = vT + (size_t)(b * KVH_ + kvh) * D_ * T_;

  // Q fragments, reg-resident: A[m=l15][d=st*32+quad*8+j], 2 m-frags.
  s16x8 qf[2][4];
#pragma unroll
  for (int mf = 0; mf < 2; ++mf) {
    const size_t qrow =
        ((size_t)(b * T_ + q0 + wq + mf * 16 + l15) * H_ + h) * D_;
#pragma unroll
    for (int st = 0; st < 4; ++st)
      qf[mf][st] = *(const s16x8*)&q[qrow + st * 32 + quad * 8];
  }

  f32x4 acc_o[2][8] = {};
  float m_r[2][4], l_r[2][4];
#pragma unroll
  for (int mf = 0; mf < 2; ++mf)
#pragma unroll
    for (int r = 0; r < 4; ++r) { m_r[mf][r] = -1.0e30f; l_r[mf][r] = 0.0f; }

  const int nkt = 2 * qt + 2;

  ATT_STAGE(0, 0);
  __syncthreads();

  for (int kt = 0; kt < nkt; ++kt) {
    const int k0 = kt * 64;
    const u16* Ks = &SM[(kt & 1) * 16384];
    const u16* Vt = Ks + 8192;

    if (kt + 1 < nkt) ATT_STAGE((kt + 1) & 1, kt + 1);

    if (k0 <= q0 + wq + 31) {  // wave-level skip of fully-masked tiles
      // ---- QK^T: S[32q x 64k] per wave, 16 kf reads feed 32 MFMAs ----
      f32x4 accs[2][4] = {};
#pragma unroll
      for (int st = 0; st < 4; ++st) {
        const int g = st * 4 + quad;
#pragma unroll
        for (int nt = 0; nt < 4; ++nt) {
          const int row = nt * 16 + l15;
          const s16x8 kf =
              *(const s16x8*)&Ks[row * 128 + ((g ^ (row & 7)) << 3)];
          accs[0][nt] = __builtin_amdgcn_mfma_f32_16x16x32_bf16(
              qf[0][st], kf, accs[0][nt], 0, 0, 0);
          accs[1][nt] = __builtin_amdgcn_mfma_f32_16x16x32_bf16(
              qf[1][st], kf, accs[1][nt], 0, 0, 0);
        }
      }

      // ---- mask + in-register online softmax (per m-frag) ----
      float al[2][4];
#pragma unroll
      for (int mf = 0; mf < 2; ++mf) {
        const bool needmask = (k0 + 63) > (q0 + wq + mf * 16);
        float pmax[4];
#pragma unroll
        for (int r = 0; r < 4; ++r) pmax[r] = -1.0e30f;
#pragma unroll
        for (int nt = 0; nt < 4; ++nt)
#pragma unroll
          for (int r = 0; r < 4; ++r) {
            float s = accs[mf][nt][r] * scale;
            if (needmask &&
                (q0 + wq + mf * 16 + quad * 4 + r) < (k0 + nt * 16 + l15))
              s = -1.0e30f;
            accs[mf][nt][r] = s;
            pmax[r] = fmaxf(pmax[r], s);
          }
#pragma unroll
        for (int r = 0; r < 4; ++r) {
          pmax[r] = fmaxf(pmax[r], __shfl_xor(pmax[r], 1));
          pmax[r] = fmaxf(pmax[r], __shfl_xor(pmax[r], 2));
          pmax[r] = fmaxf(pmax[r], __shfl_xor(pmax[r], 4));
          pmax[r] = fmaxf(pmax[r], __shfl_xor(pmax[r], 8));
          const float mnew = fmaxf(m_r[mf][r], pmax[r]);
          al[mf][r] = __expf(m_r[mf][r] - mnew);
          m_r[mf][r] = mnew;
        }
        float rsum[4] = {0.0f, 0.0f, 0.0f, 0.0f};
#pragma unroll
        for (int nt = 0; nt < 4; ++nt)
#pragma unroll
          for (int r = 0; r < 4; ++r) {
            const float p = __expf(accs[mf][nt][r] - m_r[mf][r]);
            accs[mf][nt][r] = p;
            rsum[r] += p;
          }
#pragma unroll
        for (int r = 0; r < 4; ++r) {
          rsum[r] += __shfl_xor(rsum[r], 1);
          rsum[r] += __shfl_xor(rsum[r], 2);
          rsum[r] += __shfl_xor(rsum[r], 4);
          rsum[r] += __shfl_xor(rsum[r], 8);
          l_r[mf][r] = l_r[mf][r] * al[mf][r] + rsum[r];
        }
#pragma unroll
        for (int nt2 = 0; nt2 < 8; ++nt2)
#pragma unroll
          for (int r = 0; r < 4; ++r) acc_o[mf][nt2][r] *= al[mf][r];
      }

      // ---- P -> wave-private LDS (bf16), D-layout -> A-layout ----
#pragma unroll
      for (int mf = 0; mf < 2; ++mf)
#pragma unroll
        for (int nt = 0; nt < 4; ++nt)
#pragma unroll
          for (int r = 0; r < 4; ++r) {
            const int qq = wq + mf * 16 + quad * 4 + r;
            const int c = nt * 16 + l15;
            Pl[qq * 64 + (((c >> 3) ^ (qq & 7)) << 3) + (c & 7)] =
                f2bf(accs[mf][nt][r]);
          }
      asm volatile("s_waitcnt lgkmcnt(0)" ::: "memory");

      // ---- PV: O[32q x 128d] += P[32x64] @ V[64x128] ----
      s16x8 pa[2][2];
#pragma unroll
      for (int mf = 0; mf < 2; ++mf)
#pragma unroll
        for (int ks = 0; ks < 2; ++ks) {
          const int row = wq + mf * 16 + l15;
          const int g = ks * 4 + quad;
          pa[mf][ks] = *(const s16x8*)&Pl[row * 64 + ((g ^ (row & 7)) << 3)];
        }
#pragma unroll
      for (int ks = 0; ks < 2; ++ks) {
        const int g = ks * 4 + quad;
#pragma unroll
        for (int nt2 = 0; nt2 < 8; ++nt2) {
          const int row = nt2 * 16 + l15;
          const s16x8 vf =
              *(const s16x8*)&Vt[row * 64 + ((g ^ (row & 7)) << 3)];
          acc_o[0][nt2] = __builtin_amdgcn_mfma_f32_16x16x32_bf16(
              pa[0][ks], vf, acc_o[0][nt2], 0, 0, 0);
          acc_o[1][nt2] = __builtin_amdgcn_mfma_f32_16x16x32_bf16(
              pa[1][ks], vf, acc_o[1][nt2], 0, 0, 0);
        }
      }
    }

    __syncthreads();  // drains vmcnt: buf^1 staged; all LDS reads retired
  }

  // ---- epilogue: normalize + store ----
#pragma unroll
  for (int mf = 0; mf < 2; ++mf)
#pragma unroll
    for (int r = 0; r < 4; ++r) {
      const float linv = 1.0f / l_r[mf][r];
      const size_t orow =
          ((size_t)(b * T_ + q0 + wq + mf * 16 + quad * 4 + r) * H_ + h) * D_;
#pragma unroll
      for (int nt2 = 0; nt2 < 8; ++nt2)
        o[orow + nt2 * 16 + l15] = f2bf(acc_o[mf][nt2][r] * linv);
    }
}

// Fallback: zero d_out (fp32) so an undersized workspace fails cleanly.
__global__ void zero_out_k(float* __restrict__ out, int n) {
  const int i = blockIdx.x * blockDim.x + threadIdx.x;
  if (i < n) out[i] = 0.0f;
}

// ---------------------------------------------------------------------------
extern "C" void kernel_launch(void* const* d_in, const int* in_sizes, int n_in,
                              void* d_out, int out_size, void* d_ws,
                              size_t ws_size, hipStream_t stream) {
  const void* x    = d_in[0];
  const void* cosT = d_in[1];
  const void* sinT = d_in[2];
  const void* Wq   = d_in[3];
  const void* Wk   = d_in[4];
  const void* Wv   = d_in[5];
  const void* Wo   = d_in[6];
  float* out = (float*)d_out;

  // Workspace (bf16 elems): qbuf QN | kbuf KN | vbufT KN | obuf QN |
  //   WqT 4194304 | WkT 1048576 | WvT 1048576 | WoT 4194304  = 60 MiB.
  const size_t QN = QN_;
  const size_t KN = KN_;
  const size_t WQT = (size_t)HID_ * (H_ * D_);     // 4194304
  const size_t WKT = (size_t)HID_ * (KVH_ * D_);   // 1048576
  const size_t need = (2 * QN + 2 * KN + 2 * WQT + 2 * WKT) * sizeof(u16);
  if (ws_size < need) {
    zero_out_k<<<(out_size + 255) / 256, 256, 0, stream>>>(out, out_size);
    return;
  }

  u16* qbuf  = (u16*)d_ws;
  u16* kbuf  = qbuf + QN;
  u16* vbufT = kbuf + KN;    // V^T: [b][kvh][d][t]
  u16* obuf  = vbufT + KN;
  u16* WqT   = obuf + QN;    // WqT|WkT|WvT contiguous => fused-QKV WT[3072][K]
  u16* WkT   = WqT + WQT;
  u16* WvT   = WkT + WKT;
  u16* WoT   = WvT + WKT;

  const int M = B_ * T_;  // 4096
  dim3 blk(256);

  // One-time weight transposes (W[K][N] -> WT[N][K] bf16).
  transp_k<<<dim3((H_ * D_) / 64, HID_ / 64), blk, 0, stream>>>(
      Wq, WqT, HID_, H_ * D_);
  transp_k<<<dim3((KVH_ * D_) / 64, HID_ / 64), blk, 0, stream>>>(
      Wk, WkT, HID_, KVH_ * D_);
  transp_k<<<dim3((KVH_ * D_) / 64, HID_ / 64), blk, 0, stream>>>(
      Wv, WvT, HID_, KVH_ * D_);
  transp_k<<<dim3(HID_ / 64, (H_ * D_) / 64), blk, 0, stream>>>(
      Wo, WoT, H_ * D_, HID_);

  // Fused QKV projection: N = 2048(Q) + 512(K) + 512(V^T), one GEMM.
  gemm_mfma<3><<<dim3(3072 / 128, M / 128), blk, 0, stream>>>(
      x, WqT, qbuf, M, 3072, HID_);

  const int totq = B_ * T_ * H_ * (D_ / 2);   // 4194304
  rope_bf<<<totq / 256, blk, 0, stream>>>(qbuf, cosT, sinT, H_, totq);
  const int totk = B_ * T_ * KVH_ * (D_ / 2); // 1048576
  rope_bf<<<totk / 256, blk, 0, stream>>>(kbuf, cosT, sinT, KVH_, totk);

  // MFMA flash attention v2 (QBLK=128, dbuf lds-direct staging).
  attn_mfma<<<dim3(B_ * H_, T_ / 128), blk, 0, stream>>>(
      qbuf, kbuf, vbufT, obuf);

  // Output projection (MFMA, fp32 out).
  gemm_mfma<0><<<dim3(HID_ / 128, M / 128), blk, 0, stream>>>(
      obuf, WoT, out, M, HID_, H_ * D_);
}

// Round 4
// 398.559 us; speedup vs baseline: 1.8972x; 1.0720x over previous
//
#include <hip/hip_runtime.h>
#include <hip/hip_bf16.h>

#define B_   2
#define T_   2048
#define HID_ 2048
#define H_   16
#define KVH_ 4
#define D_   128
#define GQ_  (H_ / KVH_)

#define QN_  8388608   // B*T*H*D
#define KN_  2097152   // B*T*KVH*D

typedef unsigned short u16;
typedef __attribute__((ext_vector_type(8))) unsigned short us8v;
typedef __attribute__((ext_vector_type(8))) short s16x8;   // MFMA A/B frag
typedef __attribute__((ext_vector_type(4))) float f32x4;   // MFMA C/D frag

__device__ __forceinline__ float bf2f(u16 u) {
  return __uint_as_float(((unsigned)u) << 16);
}
__device__ __forceinline__ u16 f2bf(float f) {
  unsigned x = __float_as_uint(f);
  return (u16)((x + 0x7fffu + ((x >> 16) & 1u)) >> 16);  // RNE
}

// global(16B per lane) -> LDS direct, wave-uniform dst base + lane*16.
__device__ __forceinline__ void gl2lds(const void* gp, void* lp) {
  __builtin_amdgcn_global_load_lds(
      (const __attribute__((address_space(1))) unsigned int*)gp,
      (__attribute__((address_space(3))) unsigned int*)lp, 16, 0, 0);
}

// ---------------------------------------------------------------------------
// On-device dtype probe (bf16 vs fp32), per tensor — R7-proven on this
// mixed-dtype input set. Wave-uniform, deterministic, graph-capture safe.
// ---------------------------------------------------------------------------
__device__ __forceinline__ void probe2(const void* A, const void* W, int tid,
                                       bool* abf, bool* wbf) {
  __shared__ int cA, zA, cW, zW;
  if (tid == 0) { cA = 0; zA = 0; cW = 0; zW = 0; }
  __syncthreads();
  const int i = 16384 + tid;
  {
    const u16 raw = ((const u16*)A)[i];
    const float v = bf2f(raw);
    const bool bad = !(fabsf(v) <= 1e6f) ||
                     (v != 0.0f && fabsf(v) < 1e-10f);
    if (bad) atomicAdd(&cA, 1);
    if (((tid & 1) == 0) && raw == 0) atomicAdd(&zA, 1);
  }
  {
    const u16 raw = ((const u16*)W)[i];
    const float v = bf2f(raw);
    const bool bad = !(fabsf(v) <= 1e6f) ||
                     (v != 0.0f && fabsf(v) < 1e-10f);
    if (bad) atomicAdd(&cW, 1);
    if (((tid & 1) == 0) && raw == 0) atomicAdd(&zW, 1);
  }
  __syncthreads();
  *abf = (cA < 8) && (zA < 100);
  *wbf = (cW < 8) && (zW < 100);
}

// ---------------------------------------------------------------------------
// Transpose W[K][N] (bf16 OR fp32, probed) -> WT[N][K] bf16. Runs once per
// weight; makes GEMM B-staging k-contiguous (required by MFMA B-fragment).
// ---------------------------------------------------------------------------
__global__ __launch_bounds__(256) void transp_k(const void* __restrict__ Wv_,
                                                u16* __restrict__ WT,
                                                int K, int N) {
  const int tid = threadIdx.x;
  bool wbf, dummy;
  probe2(Wv_, Wv_, tid, &wbf, &dummy);

  __shared__ float tile[64][65];
  const int kb = blockIdx.y * 64;
  const int nb = blockIdx.x * 64;

  for (int it = tid; it < 512; it += 256) {
    const int r = it >> 3;            // k-row 0..63
    const int g = it & 7;             // n-granule
    const size_t off = (size_t)(kb + r) * N + nb + g * 8;
    float f[8];
    if (wbf) {
      const us8v t8 = *(const us8v*)((const u16*)Wv_ + off);
#pragma unroll
      for (int e = 0; e < 8; ++e) f[e] = bf2f(t8[e]);
    } else {
      const float4 f0 = *(const float4*)((const float*)Wv_ + off);
      const float4 f1 = *(const float4*)((const float*)Wv_ + off + 4);
      f[0] = f0.x; f[1] = f0.y; f[2] = f0.z; f[3] = f0.w;
      f[4] = f1.x; f[5] = f1.y; f[6] = f1.z; f[7] = f1.w;
    }
#pragma unroll
    for (int e = 0; e < 8; ++e) tile[r][g * 8 + e] = f[e];
  }
  __syncthreads();
  for (int it = tid; it < 512; it += 256) {
    const int n = it >> 3;            // 0..63
    const int g = it & 7;             // k-granule
    us8v tmp;
#pragma unroll
    for (int e = 0; e < 8; ++e) tmp[e] = f2bf(tile[g * 8 + e][n]);
    *(us8v*)&WT[(size_t)(nb + n) * K + kb + g * 8] = tmp;
  }
}

// ---------------------------------------------------------------------------
// MFMA GEMM: C[M,N] = A[M,K] @ W[K,N], W pre-transposed (WT[N][K], bf16).
// A bf16 OR fp32 (probed). 128x128 tile, 4 waves (2x2), 4x4
// v_mfma_f32_16x16x32_bf16 per wave, BK=32.
// LDS: linear [128][32] u16, staged via global_load_lds w=16 with the
// granule XOR-swizzle g^((r>>1)&3) folded into the global source (m173).
// Fragment reads apply the same involution -> conflict-free ds_read_b128.
// OMODE: 0 = fp32 out row-major.
//        3 = fused QKV epilogue: col<2048 -> qbuf; col<2560 -> kbuf;
//            else -> vT[((b*KVH+kvh)*D+d)*T+t] (V^T for attention PV).
// ---------------------------------------------------------------------------
template <int OMODE>
__global__ __launch_bounds__(256) void gemm_mfma(const void* __restrict__ Av,
                                                 const u16* __restrict__ WT,
                                                 void* __restrict__ Cv,
                                                 int M, int N, int K) {
  const int tid = threadIdx.x;
  bool abf, dummy;
  probe2(Av, Av, tid, &abf, &dummy);

  __shared__ __align__(16) u16 Alds[128 * 32];
  __shared__ __align__(16) u16 Blds[128 * 32];

  const int m0 = blockIdx.y * 128;
  const int n0 = blockIdx.x * 128;
  const int wave = tid >> 6;
  const int lane = tid & 63;
  const int wm = (wave >> 1) * 64;
  const int wn = (wave & 1) * 64;
  const int lrow = lane & 15;
  const int lq = lane >> 4;

  f32x4 acc[4][4] = {};

  for (int k0 = 0; k0 < K; k0 += 32) {
    __syncthreads();  // previous iteration's LDS reads complete
    if (abf) {
#pragma unroll
      for (int p = 0; p < 2; ++p) {
        const int it = tid + p * 256;
        const int r = it >> 2, g = it & 3;
        const int gs = g ^ ((r >> 1) & 3);   // source pre-swizzle
        gl2lds((const u16*)Av + (size_t)(m0 + r) * K + k0 + gs * 8,
               &Alds[((tid & ~63) + p * 256) * 8]);
      }
    } else {
#pragma unroll
      for (int p = 0; p < 2; ++p) {
        const int it = tid + p * 256;
        const int r = it >> 2, g = it & 3;
        const int gs = g ^ ((r >> 1) & 3);
        const size_t off = (size_t)(m0 + r) * K + k0 + gs * 8;
        const float4 f0 = *(const float4*)((const float*)Av + off);
        const float4 f1 = *(const float4*)((const float*)Av + off + 4);
        us8v tmp;
        tmp[0] = f2bf(f0.x); tmp[1] = f2bf(f0.y);
        tmp[2] = f2bf(f0.z); tmp[3] = f2bf(f0.w);
        tmp[4] = f2bf(f1.x); tmp[5] = f2bf(f1.y);
        tmp[6] = f2bf(f1.z); tmp[7] = f2bf(f1.w);
        *(us8v*)&Alds[r * 32 + g * 8] = tmp;
      }
    }
#pragma unroll
    for (int p = 0; p < 2; ++p) {
      const int it = tid + p * 256;
      const int n = it >> 2, g = it & 3;
      const int gs = g ^ ((n >> 1) & 3);
      gl2lds(WT + (size_t)(n0 + n) * K + k0 + gs * 8,
             &Blds[((tid & ~63) + p * 256) * 8]);
    }
    __syncthreads();  // compiler drains vmcnt+lgkmcnt here

    s16x8 af[4], bfr[4];
#pragma unroll
    for (int mi = 0; mi < 4; ++mi) {
      const int row = wm + 16 * mi + lrow;
      af[mi] = *(const s16x8*)&Alds[row * 32 + ((lq ^ ((row >> 1) & 3)) * 8)];
    }
#pragma unroll
    for (int ni = 0; ni < 4; ++ni) {
      const int row = wn + 16 * ni + lrow;
      bfr[ni] = *(const s16x8*)&Blds[row * 32 + ((lq ^ ((row >> 1) & 3)) * 8)];
    }
#pragma unroll
    for (int mi = 0; mi < 4; ++mi)
#pragma unroll
      for (int ni = 0; ni < 4; ++ni)
        acc[mi][ni] = __builtin_amdgcn_mfma_f32_16x16x32_bf16(
            af[mi], bfr[ni], acc[mi][ni], 0, 0, 0);
  }

  // epilogue: D col=lane&15, row=quad*4+reg
#pragma unroll
  for (int mi = 0; mi < 4; ++mi) {
#pragma unroll
    for (int ni = 0; ni < 4; ++ni) {
      const int row0 = m0 + wm + 16 * mi + lq * 4;
      const int col = n0 + wn + 16 * ni + lrow;
#pragma unroll
      for (int r = 0; r < 4; ++r) {
        const int row = row0 + r;
        if (OMODE == 0) {
          ((float*)Cv)[(size_t)row * N + col] = acc[mi][ni][r];
        } else {
          const u16 val = f2bf(acc[mi][ni][r]);
          if (col < 2048) {
            ((u16*)Cv)[(size_t)row * 2048 + col] = val;           // qbuf
          } else if (col < 2560) {
            ((u16*)Cv)[QN_ + (size_t)row * 512 + (col - 2048)] = val;  // kbuf
          } else {
            const int c = col - 2560;          // 0..511
            const int kvh = c >> 7;
            const int d = c & 127;
            const int bb = row >> 11;          // T_ == 2048
            const int tt = row & (T_ - 1);
            ((u16*)Cv)[QN_ + KN_ +
                       ((size_t)(bb * KVH_ + kvh) * D_ + d) * T_ + tt] = val;
          }
        }
      }
    }
  }
}

// ---------------------------------------------------------------------------
// RoPE (rotate-half), in place on a BF16 (B, T, NH, D) workspace tensor.
// ---------------------------------------------------------------------------
__global__ __launch_bounds__(256) void rope_bf(u16* __restrict__ t,
                                               const void* __restrict__ cosT,
                                               const void* __restrict__ sinT,
                                               int NH, int total) {
  const int tid = threadIdx.x;
  bool cbf, sbf;
  probe2(cosT, sinT, tid, &cbf, &sbf);

  const int idx = blockIdx.x * blockDim.x + tid;
  if (idx >= total) return;
  const int d = idx & 63;
  const int rest = idx >> 6;
  const int tt = (rest / NH) % T_;
  const size_t base = (size_t)rest * D_;
  const int ci = tt * D_ + d;
  float c1, s1, c2, s2;
  if (cbf) {
    c1 = bf2f(((const u16*)cosT)[ci]);
    c2 = bf2f(((const u16*)cosT)[ci + 64]);
  } else {
    c1 = ((const float*)cosT)[ci];
    c2 = ((const float*)cosT)[ci + 64];
  }
  if (sbf) {
    s1 = bf2f(((const u16*)sinT)[ci]);
    s2 = bf2f(((const u16*)sinT)[ci + 64]);
  } else {
    s1 = ((const float*)sinT)[ci];
    s2 = ((const float*)sinT)[ci + 64];
  }
  const float x1 = bf2f(t[base + d]);
  const float x2 = bf2f(t[base + d + 64]);
  t[base + d] = f2bf(x1 * c1 - x2 * s1);
  t[base + d + 64] = f2bf(x2 * c2 + x1 * s2);
}

// ---------------------------------------------------------------------------
// Causal GQA flash attention, MFMA v3 (this round):
//  - BALANCED PAIRING: block (bh, i) handles q-tiles hi=31-i (waves 0-3,
//    16 rows each) and lo=i (waves 4-7, active while kt<=i). Every block
//    computes exactly 33 tile-units -> no early-finishing blocks, CUs keep
//    16 waves (4/SIMD) instead of collapsing to 1 wave/SIMD (R3's 12.4%
//    occupancy tail).
//  - 512 threads / 8 waves, 2 blocks/CU (80KB LDS).
//  - K/V dbuf staged via global_load_lds w=16 with pre-swizzled source.
//  - defer-max (T13, THR=8): skip O-rescale when max doesn't grow.
//  - setprio around MFMA clusters (T5); sched_barrier after lgkmcnt (r#18).
// ---------------------------------------------------------------------------
#define ATT_STAGE(bi, ktile)                                                  \
  do {                                                                        \
    const int _k0 = (ktile) * 64;                                             \
    u16* _bk = &SM[(bi) * 16384];                                             \
    _Pragma("unroll") for (int _p = 0; _p < 2; ++_p) {                        \
      const int _it = tid + _p * 512;                                         \
      const int _r = _it >> 4, _s = _it & 15;                                 \
      gl2lds(kp + (size_t)(_k0 + _r) * (KVH_ * D_) + ((_s ^ (_r & 7)) * 8),   \
             &_bk[((tid & ~63) + _p * 512) * 8]);                             \
    }                                                                         \
    _Pragma("unroll") for (int _p = 0; _p < 2; ++_p) {                        \
      const int _it = tid + _p * 512;                                         \
      const int _r = _it >> 3, _s = _it & 7;                                  \
      gl2lds(vp + (size_t)_r * T_ + _k0 + ((_s ^ (_r & 7)) * 8),              \
             &_bk[8192 + ((tid & ~63) + _p * 512) * 8]);                      \
    }                                                                         \
  } while (0)

__global__ __launch_bounds__(512, 4) void attn_mfma(
    const u16* __restrict__ q, const u16* __restrict__ k,
    const u16* __restrict__ vT, u16* __restrict__ o) {
  const float scale = 0.08838834764831845f;  // 1/sqrt(128)
  const int tid = threadIdx.x;
  const int ip = blockIdx.y;                 // pair index 0..15 (heavy first)
  const int bh = blockIdx.x;
  const int b = bh >> 4;
  const int h = bh & 15;
  const int kvh = h >> 2;
  const int hi0 = 64 * (31 - ip);
  const int lo0 = 64 * ip;

  __shared__ __align__(16) u16 SM[2 * 16384];  // dbuf {Ks 64x128, Vt 128x64}
  __shared__ __align__(16) u16 Pl[128 * 64];   // P (bf16), granule-XOR

  const int wave = tid >> 6;                 // 0..7
  const int lane = tid & 63;
  const int l15 = lane & 15;
  const int quad = lane >> 4;
  const bool isHi = wave < 4;
  const int rowbase = isHi ? (hi0 + 16 * wave) : (lo0 + 16 * (wave - 4));
  const int pr0 = 16 * wave;                 // Pl row base, wave-private

  const u16* kp = k + ((size_t)b * T_ * KVH_ + kvh) * D_;
  const u16* vp = vT + (size_t)(b * KVH_ + kvh) * D_ * T_;

  // Q fragment, reg-resident: A[m=l15][d=st*32+quad*8+j].
  s16x8 qf[4];
  {
    const size_t qrow = ((size_t)(b * T_ + rowbase + l15) * H_ + h) * D_;
#pragma unroll
    for (int st = 0; st < 4; ++st)
      qf[st] = *(const s16x8*)&q[qrow + st * 32 + quad * 8];
  }

  f32x4 acc_o[8] = {};
  float m_r[4], l_r[4];
#pragma unroll
  for (int r = 0; r < 4; ++r) { m_r[r] = -1.0e30f; l_r[r] = 0.0f; }

  const int nkt = 32 - ip;  // hi tile count; lo active while kt <= ip

  ATT_STAGE(0, 0);
  __syncthreads();

  for (int kt = 0; kt < nkt; ++kt) {
    const int k0 = kt * 64;
    const u16* Ks = &SM[(kt & 1) * 16384];
    const u16* Vt = Ks + 8192;

    if (kt + 1 < nkt) ATT_STAGE((kt + 1) & 1, kt + 1);

    const bool active = isHi || (kt <= ip);  // wave-uniform
    if (active) {
      // ---- QK^T: S[16q x 64k] ----
      f32x4 accs[4] = {};
      __builtin_amdgcn_s_setprio(1);
#pragma unroll
      for (int st = 0; st < 4; ++st) {
        const int g = st * 4 + quad;
#pragma unroll
        for (int nt = 0; nt < 4; ++nt) {
          const int row = nt * 16 + l15;
          const s16x8 kf =
              *(const s16x8*)&Ks[row * 128 + ((g ^ (row & 7)) << 3)];
          accs[nt] = __builtin_amdgcn_mfma_f32_16x16x32_bf16(qf[st], kf,
                                                             accs[nt], 0, 0,
                                                             0);
        }
      }
      __builtin_amdgcn_s_setprio(0);

      // ---- mask + in-register online softmax (defer-max) ----
      const bool needmask = (k0 + 63) > rowbase;
      float pmax[4];
#pragma unroll
      for (int r = 0; r < 4; ++r) pmax[r] = -1.0e30f;
#pragma unroll
      for (int nt = 0; nt < 4; ++nt)
#pragma unroll
        for (int r = 0; r < 4; ++r) {
          float s = accs[nt][r] * scale;
          if (needmask && (rowbase + quad * 4 + r) < (k0 + nt * 16 + l15))
            s = -1.0e30f;
          accs[nt][r] = s;
          pmax[r] = fmaxf(pmax[r], s);
        }
#pragma unroll
      for (int r = 0; r < 4; ++r) {
        pmax[r] = fmaxf(pmax[r], __shfl_xor(pmax[r], 1));
        pmax[r] = fmaxf(pmax[r], __shfl_xor(pmax[r], 2));
        pmax[r] = fmaxf(pmax[r], __shfl_xor(pmax[r], 4));
        pmax[r] = fmaxf(pmax[r], __shfl_xor(pmax[r], 8));
      }
      int okd = 1;
#pragma unroll
      for (int r = 0; r < 4; ++r)
        okd &= (pmax[r] <= m_r[r] + 8.0f) ? 1 : 0;
      const int defer = __all(okd);
      float al[4];
      if (!defer) {
#pragma unroll
        for (int r = 0; r < 4; ++r) {
          const float mnew = fmaxf(m_r[r], pmax[r]);
          al[r] = __expf(m_r[r] - mnew);
          m_r[r] = mnew;
        }
      } else {
#pragma unroll
        for (int r = 0; r < 4; ++r) al[r] = 1.0f;
      }
      float rsum[4] = {0.0f, 0.0f, 0.0f, 0.0f};
#pragma unroll
      for (int nt = 0; nt < 4; ++nt)
#pragma unroll
        for (int r = 0; r < 4; ++r) {
          const float p = __expf(accs[nt][r] - m_r[r]);
          accs[nt][r] = p;
          rsum[r] += p;
        }
#pragma unroll
      for (int r = 0; r < 4; ++r) {
        rsum[r] += __shfl_xor(rsum[r], 1);
        rsum[r] += __shfl_xor(rsum[r], 2);
        rsum[r] += __shfl_xor(rsum[r], 4);
        rsum[r] += __shfl_xor(rsum[r], 8);
        l_r[r] = l_r[r] * al[r] + rsum[r];
      }
      if (!defer) {
#pragma unroll
        for (int nt2 = 0; nt2 < 8; ++nt2)
#pragma unroll
          for (int r = 0; r < 4; ++r) acc_o[nt2][r] *= al[r];
      }

      // ---- P -> wave-private LDS rows (bf16), D-layout -> A-layout ----
#pragma unroll
      for (int nt = 0; nt < 4; ++nt)
#pragma unroll
        for (int r = 0; r < 4; ++r) {
          const int pr = pr0 + quad * 4 + r;
          const int c = nt * 16 + l15;
          Pl[pr * 64 + (((c >> 3) ^ (pr & 7)) << 3) + (c & 7)] =
              f2bf(accs[nt][r]);
        }
      asm volatile("s_waitcnt lgkmcnt(0)" ::: "memory");
      __builtin_amdgcn_sched_barrier(0);

      // ---- PV: O[16q x 128d] += P[16x64] @ V[64x128] ----
      s16x8 pa[2];
#pragma unroll
      for (int ks = 0; ks < 2; ++ks) {
        const int row = pr0 + l15;
        const int g = ks * 4 + quad;
        pa[ks] = *(const s16x8*)&Pl[row * 64 + ((g ^ (row & 7)) << 3)];
      }
      __builtin_amdgcn_s_setprio(1);
#pragma unroll
      for (int ks = 0; ks < 2; ++ks) {
        const int g = ks * 4 + quad;
#pragma unroll
        for (int nt2 = 0; nt2 < 8; ++nt2) {
          const int row = nt2 * 16 + l15;
          const s16x8 vf =
              *(const s16x8*)&Vt[row * 64 + ((g ^ (row & 7)) << 3)];
          acc_o[nt2] = __builtin_amdgcn_mfma_f32_16x16x32_bf16(pa[ks], vf,
                                                               acc_o[nt2], 0,
                                                               0, 0);
        }
      }
      __builtin_amdgcn_s_setprio(0);
    }

    __syncthreads();  // drains vmcnt: buf^1 staged; all LDS reads retired
  }

  // ---- epilogue: normalize + store ----
#pragma unroll
  for (int r = 0; r < 4; ++r) {
    const float linv = 1.0f / l_r[r];
    const size_t orow =
        ((size_t)(b * T_ + rowbase + quad * 4 + r) * H_ + h) * D_;
#pragma unroll
    for (int nt2 = 0; nt2 < 8; ++nt2)
      o[orow + nt2 * 16 + l15] = f2bf(acc_o[nt2][r] * linv);
  }
}

// Fallback: zero d_out (fp32) so an undersized workspace fails cleanly.
__global__ void zero_out_k(float* __restrict__ out, int n) {
  const int i = blockIdx.x * blockDim.x + threadIdx.x;
  if (i < n) out[i] = 0.0f;
}

// ---------------------------------------------------------------------------
extern "C" void kernel_launch(void* const* d_in, const int* in_sizes, int n_in,
                              void* d_out, int out_size, void* d_ws,
                              size_t ws_size, hipStream_t stream) {
  const void* x    = d_in[0];
  const void* cosT = d_in[1];
  const void* sinT = d_in[2];
  const void* Wq   = d_in[3];
  const void* Wk   = d_in[4];
  const void* Wv   = d_in[5];
  const void* Wo   = d_in[6];
  float* out = (float*)d_out;

  // Workspace (bf16 elems): qbuf QN | kbuf KN | vbufT KN | obuf QN |
  //   WqT 4194304 | WkT 1048576 | WvT 1048576 | WoT 4194304  = 60 MiB.
  const size_t QN = QN_;
  const size_t KN = KN_;
  const size_t WQT = (size_t)HID_ * (H_ * D_);     // 4194304
  const size_t WKT = (size_t)HID_ * (KVH_ * D_);   // 1048576
  const size_t need = (2 * QN + 2 * KN + 2 * WQT + 2 * WKT) * sizeof(u16);
  if (ws_size < need) {
    zero_out_k<<<(out_size + 255) / 256, 256, 0, stream>>>(out, out_size);
    return;
  }

  u16* qbuf  = (u16*)d_ws;
  u16* kbuf  = qbuf + QN;
  u16* vbufT = kbuf + KN;    // V^T: [b][kvh][d][t]
  u16* obuf  = vbufT + KN;
  u16* WqT   = obuf + QN;    // WqT|WkT|WvT contiguous => fused-QKV WT[3072][K]
  u16* WkT   = WqT + WQT;
  u16* WvT   = WkT + WKT;
  u16* WoT   = WvT + WKT;

  const int M = B_ * T_;  // 4096
  dim3 blk(256);

  // One-time weight transposes (W[K][N] -> WT[N][K] bf16).
  transp_k<<<dim3((H_ * D_) / 64, HID_ / 64), blk, 0, stream>>>(
      Wq, WqT, HID_, H_ * D_);
  transp_k<<<dim3((KVH_ * D_) / 64, HID_ / 64), blk, 0, stream>>>(
      Wk, WkT, HID_, KVH_ * D_);
  transp_k<<<dim3((KVH_ * D_) / 64, HID_ / 64), blk, 0, stream>>>(
      Wv, WvT, HID_, KVH_ * D_);
  transp_k<<<dim3(HID_ / 64, (H_ * D_) / 64), blk, 0, stream>>>(
      Wo, WoT, H_ * D_, HID_);

  // Fused QKV projection: N = 2048(Q) + 512(K) + 512(V^T), one GEMM.
  gemm_mfma<3><<<dim3(3072 / 128, M / 128), blk, 0, stream>>>(
      x, WqT, qbuf, M, 3072, HID_);

  const int totq = B_ * T_ * H_ * (D_ / 2);   // 4194304
  rope_bf<<<totq / 256, blk, 0, stream>>>(qbuf, cosT, sinT, H_, totq);
  const int totk = B_ * T_ * KVH_ * (D_ / 2); // 1048576
  rope_bf<<<totk / 256, blk, 0, stream>>>(kbuf, cosT, sinT, KVH_, totk);

  // MFMA flash attention v3 (paired q-tiles, 8 waves, dbuf staging).
  attn_mfma<<<dim3(B_ * H_, 16), dim3(512), 0, stream>>>(
      qbuf, kbuf, vbufT, obuf);

  // Output projection (MFMA, fp32 out).
  gemm_mfma<0><<<dim3(HID_ / 128, M / 128), blk, 0, stream>>>(
      obuf, WoT, out, M, HID_, H_ * D_);
}

// Round 5
// 349.547 us; speedup vs baseline: 2.1632x; 1.1402x over previous
//
#include <hip/hip_runtime.h>
#include <hip/hip_bf16.h>

#define B_   2
#define T_   2048
#define HID_ 2048
#define H_   16
#define KVH_ 4
#define D_   128
#define GQ_  (H_ / KVH_)

#define QN_  8388608   // B*T*H*D
#define KN_  2097152   // B*T*KVH*D

typedef unsigned short u16;
typedef __attribute__((ext_vector_type(8))) unsigned short us8v;
typedef __attribute__((ext_vector_type(8))) short s16x8;   // MFMA A/B frag
typedef __attribute__((ext_vector_type(4))) float f32x4;   // MFMA C/D frag

__device__ __forceinline__ float bf2f(u16 u) {
  return __uint_as_float(((unsigned)u) << 16);
}
__device__ __forceinline__ u16 f2bf(float f) {
  unsigned x = __float_as_uint(f);
  return (u16)((x + 0x7fffu + ((x >> 16) & 1u)) >> 16);  // RNE
}

// global(16B per lane) -> LDS direct, wave-uniform dst base + lane*16.
__device__ __forceinline__ void gl2lds(const void* gp, void* lp) {
  __builtin_amdgcn_global_load_lds(
      (const __attribute__((address_space(1))) unsigned int*)gp,
      (__attribute__((address_space(3))) unsigned int*)lp, 16, 0, 0);
}

// ---------------------------------------------------------------------------
// On-device dtype probe (bf16 vs fp32), per tensor — R7-proven on this
// mixed-dtype input set. Wave-uniform, deterministic, graph-capture safe.
// ---------------------------------------------------------------------------
__device__ __forceinline__ void probe2(const void* A, const void* W, int tid,
                                       bool* abf, bool* wbf) {
  __shared__ int cA, zA, cW, zW;
  if (tid == 0) { cA = 0; zA = 0; cW = 0; zW = 0; }
  __syncthreads();
  const int i = 16384 + tid;
  {
    const u16 raw = ((const u16*)A)[i];
    const float v = bf2f(raw);
    const bool bad = !(fabsf(v) <= 1e6f) ||
                     (v != 0.0f && fabsf(v) < 1e-10f);
    if (bad) atomicAdd(&cA, 1);
    if (((tid & 1) == 0) && raw == 0) atomicAdd(&zA, 1);
  }
  {
    const u16 raw = ((const u16*)W)[i];
    const float v = bf2f(raw);
    const bool bad = !(fabsf(v) <= 1e6f) ||
                     (v != 0.0f && fabsf(v) < 1e-10f);
    if (bad) atomicAdd(&cW, 1);
    if (((tid & 1) == 0) && raw == 0) atomicAdd(&zW, 1);
  }
  __syncthreads();
  *abf = (cA < 8) && (zA < 100);
  *wbf = (cW < 8) && (zW < 100);
}

// ---------------------------------------------------------------------------
// Transpose W[K][N] (bf16 OR fp32, probed) -> WT[N][K] bf16. Runs once per
// weight; makes GEMM B-staging k-contiguous (required by MFMA B-fragment).
// ---------------------------------------------------------------------------
__global__ __launch_bounds__(256) void transp_k(const void* __restrict__ Wv_,
                                                u16* __restrict__ WT,
                                                int K, int N) {
  const int tid = threadIdx.x;
  bool wbf, dummy;
  probe2(Wv_, Wv_, tid, &wbf, &dummy);

  __shared__ float tile[64][65];
  const int kb = blockIdx.y * 64;
  const int nb = blockIdx.x * 64;

  for (int it = tid; it < 512; it += 256) {
    const int r = it >> 3;            // k-row 0..63
    const int g = it & 7;             // n-granule
    const size_t off = (size_t)(kb + r) * N + nb + g * 8;
    float f[8];
    if (wbf) {
      const us8v t8 = *(const us8v*)((const u16*)Wv_ + off);
#pragma unroll
      for (int e = 0; e < 8; ++e) f[e] = bf2f(t8[e]);
    } else {
      const float4 f0 = *(const float4*)((const float*)Wv_ + off);
      const float4 f1 = *(const float4*)((const float*)Wv_ + off + 4);
      f[0] = f0.x; f[1] = f0.y; f[2] = f0.z; f[3] = f0.w;
      f[4] = f1.x; f[5] = f1.y; f[6] = f1.z; f[7] = f1.w;
    }
#pragma unroll
    for (int e = 0; e < 8; ++e) tile[r][g * 8 + e] = f[e];
  }
  __syncthreads();
  for (int it = tid; it < 512; it += 256) {
    const int n = it >> 3;            // 0..63
    const int g = it & 7;             // k-granule
    us8v tmp;
#pragma unroll
    for (int e = 0; e < 8; ++e) tmp[e] = f2bf(tile[g * 8 + e][n]);
    *(us8v*)&WT[(size_t)(nb + n) * K + kb + g * 8] = tmp;
  }
}

// ---------------------------------------------------------------------------
// MFMA GEMM: C[M,N] = A[M,K] @ W[K,N], W pre-transposed (WT[N][K], bf16).
// A bf16 OR fp32 (probed). 128x128 tile, 4 waves (2x2), 4x4
// v_mfma_f32_16x16x32_bf16 per wave, BK=32.
// LDS: linear [128][32] u16, staged via global_load_lds w=16 with the
// granule XOR-swizzle g^((r>>1)&3) folded into the global source (m173).
// Fragment reads apply the same involution -> conflict-free ds_read_b128.
// OMODE: 0 = fp32 out row-major.
//        3 = fused QKV epilogue: col<2048 -> qbuf; col<2560 -> kbuf;
//            else -> vT[((b*KVH+kvh)*D+d)*T+t] (V^T for attention PV).
// ---------------------------------------------------------------------------
template <int OMODE>
__global__ __launch_bounds__(256) void gemm_mfma(const void* __restrict__ Av,
                                                 const u16* __restrict__ WT,
                                                 void* __restrict__ Cv,
                                                 int M, int N, int K) {
  const int tid = threadIdx.x;
  bool abf, dummy;
  probe2(Av, Av, tid, &abf, &dummy);

  __shared__ __align__(16) u16 Alds[128 * 32];
  __shared__ __align__(16) u16 Blds[128 * 32];

  const int m0 = blockIdx.y * 128;
  const int n0 = blockIdx.x * 128;
  const int wave = tid >> 6;
  const int lane = tid & 63;
  const int wm = (wave >> 1) * 64;
  const int wn = (wave & 1) * 64;
  const int lrow = lane & 15;
  const int lq = lane >> 4;

  f32x4 acc[4][4] = {};

  for (int k0 = 0; k0 < K; k0 += 32) {
    __syncthreads();  // previous iteration's LDS reads complete
    if (abf) {
#pragma unroll
      for (int p = 0; p < 2; ++p) {
        const int it = tid + p * 256;
        const int r = it >> 2, g = it & 3;
        const int gs = g ^ ((r >> 1) & 3);   // source pre-swizzle
        gl2lds((const u16*)Av + (size_t)(m0 + r) * K + k0 + gs * 8,
               &Alds[((tid & ~63) + p * 256) * 8]);
      }
    } else {
#pragma unroll
      for (int p = 0; p < 2; ++p) {
        const int it = tid + p * 256;
        const int r = it >> 2, g = it & 3;
        const int gs = g ^ ((r >> 1) & 3);
        const size_t off = (size_t)(m0 + r) * K + k0 + gs * 8;
        const float4 f0 = *(const float4*)((const float*)Av + off);
        const float4 f1 = *(const float4*)((const float*)Av + off + 4);
        us8v tmp;
        tmp[0] = f2bf(f0.x); tmp[1] = f2bf(f0.y);
        tmp[2] = f2bf(f0.z); tmp[3] = f2bf(f0.w);
        tmp[4] = f2bf(f1.x); tmp[5] = f2bf(f1.y);
        tmp[6] = f2bf(f1.z); tmp[7] = f2bf(f1.w);
        *(us8v*)&Alds[r * 32 + g * 8] = tmp;
      }
    }
#pragma unroll
    for (int p = 0; p < 2; ++p) {
      const int it = tid + p * 256;
      const int n = it >> 2, g = it & 3;
      const int gs = g ^ ((n >> 1) & 3);
      gl2lds(WT + (size_t)(n0 + n) * K + k0 + gs * 8,
             &Blds[((tid & ~63) + p * 256) * 8]);
    }
    __syncthreads();  // compiler drains vmcnt+lgkmcnt here

    s16x8 af[4], bfr[4];
#pragma unroll
    for (int mi = 0; mi < 4; ++mi) {
      const int row = wm + 16 * mi + lrow;
      af[mi] = *(const s16x8*)&Alds[row * 32 + ((lq ^ ((row >> 1) & 3)) * 8)];
    }
#pragma unroll
    for (int ni = 0; ni < 4; ++ni) {
      const int row = wn + 16 * ni + lrow;
      bfr[ni] = *(const s16x8*)&Blds[row * 32 + ((lq ^ ((row >> 1) & 3)) * 8)];
    }
#pragma unroll
    for (int mi = 0; mi < 4; ++mi)
#pragma unroll
      for (int ni = 0; ni < 4; ++ni)
        acc[mi][ni] = __builtin_amdgcn_mfma_f32_16x16x32_bf16(
            af[mi], bfr[ni], acc[mi][ni], 0, 0, 0);
  }

  // epilogue: D col=lane&15, row=quad*4+reg
#pragma unroll
  for (int mi = 0; mi < 4; ++mi) {
#pragma unroll
    for (int ni = 0; ni < 4; ++ni) {
      const int row0 = m0 + wm + 16 * mi + lq * 4;
      const int col = n0 + wn + 16 * ni + lrow;
#pragma unroll
      for (int r = 0; r < 4; ++r) {
        const int row = row0 + r;
        if (OMODE == 0) {
          ((float*)Cv)[(size_t)row * N + col] = acc[mi][ni][r];
        } else {
          const u16 val = f2bf(acc[mi][ni][r]);
          if (col < 2048) {
            ((u16*)Cv)[(size_t)row * 2048 + col] = val;           // qbuf
          } else if (col < 2560) {
            ((u16*)Cv)[QN_ + (size_t)row * 512 + (col - 2048)] = val;  // kbuf
          } else {
            const int c = col - 2560;          // 0..511
            const int kvh = c >> 7;
            const int d = c & 127;
            const int bb = row >> 11;          // T_ == 2048
            const int tt = row & (T_ - 1);
            ((u16*)Cv)[QN_ + KN_ +
                       ((size_t)(bb * KVH_ + kvh) * D_ + d) * T_ + tt] = val;
          }
        }
      }
    }
  }
}

// ---------------------------------------------------------------------------
// RoPE (rotate-half), in place on a BF16 (B, T, NH, D) workspace tensor.
// qs: output scale (1/sqrt(D) for Q — folds the attention scale into Q,
// saving 16 VALU muls per attn wave-tile; 1.0 for K).
// ---------------------------------------------------------------------------
__global__ __launch_bounds__(256) void rope_bf(u16* __restrict__ t,
                                               const void* __restrict__ cosT,
                                               const void* __restrict__ sinT,
                                               int NH, int total, float qs) {
  const int tid = threadIdx.x;
  bool cbf, sbf;
  probe2(cosT, sinT, tid, &cbf, &sbf);

  const int idx = blockIdx.x * blockDim.x + tid;
  if (idx >= total) return;
  const int d = idx & 63;
  const int rest = idx >> 6;
  const int tt = (rest / NH) % T_;
  const size_t base = (size_t)rest * D_;
  const int ci = tt * D_ + d;
  float c1, s1, c2, s2;
  if (cbf) {
    c1 = bf2f(((const u16*)cosT)[ci]);
    c2 = bf2f(((const u16*)cosT)[ci + 64]);
  } else {
    c1 = ((const float*)cosT)[ci];
    c2 = ((const float*)cosT)[ci + 64];
  }
  if (sbf) {
    s1 = bf2f(((const u16*)sinT)[ci]);
    s2 = bf2f(((const u16*)sinT)[ci + 64]);
  } else {
    s1 = ((const float*)sinT)[ci];
    s2 = ((const float*)sinT)[ci + 64];
  }
  const float x1 = bf2f(t[base + d]);
  const float x2 = bf2f(t[base + d + 64]);
  t[base + d] = f2bf((x1 * c1 - x2 * s1) * qs);
  t[base + d + 64] = f2bf((x2 * c2 + x1 * s2) * qs);
}

// ---------------------------------------------------------------------------
// Causal GQA flash attention, MFMA v4 (this round):
//  - SWAPPED QK^T (T12 idea): mfma(kf, qf) -> lane holds S[q=l15][16 of 64 k]
//    (k = nt*16 + quad*4 + r). Same fragments as before (Q frag already has
//    B-layout). Softmax row-reduce = in-lane tree + 2 shfl_xor(16,32)
//    instead of 32 ds-permutes; P-pack via v_cvt_pk_bf16_f32 (8 asm ops vs
//    48 bit-twiddle); P-writes 4x ds_write_b64 vs 16x ds_write_b16; scale
//    pre-folded into Q; mask = wave-uniform branch (1-2 tiles/wave).
//    m/l are per-lane scalars; rare un-deferred rescale redistributes al
//    across the quad dim with 4 bpermutes.
//  - Everything else (pairing, 8 waves, dbuf global_load_lds staging,
//    defer-max, setprio) unchanged from v3.
// ---------------------------------------------------------------------------
#define ATT_STAGE(bi, ktile)                                                  \
  do {                                                                        \
    const int _k0 = (ktile) * 64;                                             \
    u16* _bk = &SM[(bi) * 16384];                                             \
    _Pragma("unroll") for (int _p = 0; _p < 2; ++_p) {                        \
      const int _it = tid + _p * 512;                                         \
      const int _r = _it >> 4, _s = _it & 15;                                 \
      gl2lds(kp + (size_t)(_k0 + _r) * (KVH_ * D_) + ((_s ^ (_r & 7)) * 8),   \
             &_bk[((tid & ~63) + _p * 512) * 8]);                             \
    }                                                                         \
    _Pragma("unroll") for (int _p = 0; _p < 2; ++_p) {                        \
      const int _it = tid + _p * 512;                                         \
      const int _r = _it >> 3, _s = _it & 7;                                  \
      gl2lds(vp + (size_t)_r * T_ + _k0 + ((_s ^ (_r & 7)) * 8),              \
             &_bk[8192 + ((tid & ~63) + _p * 512) * 8]);                      \
    }                                                                         \
  } while (0)

__global__ __launch_bounds__(512, 4) void attn_mfma(
    const u16* __restrict__ q, const u16* __restrict__ k,
    const u16* __restrict__ vT, u16* __restrict__ o) {
  const int tid = threadIdx.x;
  const int ip = blockIdx.y;                 // pair index 0..15
  const int bh = blockIdx.x;
  const int b = bh >> 4;
  const int h = bh & 15;
  const int kvh = h >> 2;
  const int hi0 = 64 * (31 - ip);
  const int lo0 = 64 * ip;

  __shared__ __align__(16) u16 SM[2 * 16384];  // dbuf {Ks 64x128, Vt 128x64}
  __shared__ __align__(16) u16 Pl[128 * 64];   // P (bf16), granule-XOR

  const int wave = tid >> 6;                 // 0..7
  const int lane = tid & 63;
  const int l15 = lane & 15;
  const int quad = lane >> 4;
  const bool isHi = wave < 4;
  const int rowbase = isHi ? (hi0 + 16 * wave) : (lo0 + 16 * (wave - 4));
  const int pr0 = 16 * wave;                 // Pl row base, wave-private

  const u16* kp = k + ((size_t)b * T_ * KVH_ + kvh) * D_;
  const u16* vp = vT + (size_t)(b * KVH_ + kvh) * D_ * T_;

  // Q fragment, reg-resident: B-layout [n=q=l15][d=st*32+quad*8+j].
  s16x8 qf[4];
  {
    const size_t qrow = ((size_t)(b * T_ + rowbase + l15) * H_ + h) * D_;
#pragma unroll
    for (int st = 0; st < 4; ++st)
      qf[st] = *(const s16x8*)&q[qrow + st * 32 + quad * 8];
  }

  f32x4 acc_o[8] = {};   // PV out: row q=quad*4+r, col d=nt2*16+l15
  float m_s = -1.0e30f, l_s = 0.0f;   // per-lane state for q = rowbase+l15

  const int nkt = 32 - ip;  // hi tile count; lo active while kt <= ip

  ATT_STAGE(0, 0);
  __syncthreads();

  for (int kt = 0; kt < nkt; ++kt) {
    const int k0 = kt * 64;
    const u16* Ks = &SM[(kt & 1) * 16384];
    const u16* Vt = Ks + 8192;

    if (kt + 1 < nkt) ATT_STAGE((kt + 1) & 1, kt + 1);

    const bool active = isHi || (kt <= ip);  // wave-uniform
    if (active) {
      // ---- swapped QK^T: lane holds S[q=l15][k=nt*16+quad*4+r] ----
      f32x4 accs[4] = {};
      __builtin_amdgcn_s_setprio(1);
#pragma unroll
      for (int st = 0; st < 4; ++st) {
        const int g = st * 4 + quad;
#pragma unroll
        for (int nt = 0; nt < 4; ++nt) {
          const int row = nt * 16 + l15;
          const s16x8 kf =
              *(const s16x8*)&Ks[row * 128 + ((g ^ (row & 7)) << 3)];
          accs[nt] = __builtin_amdgcn_mfma_f32_16x16x32_bf16(kf, qf[st],
                                                             accs[nt], 0, 0,
                                                             0);
        }
      }
      __builtin_amdgcn_s_setprio(0);

      // ---- causal mask: wave-uniform branch, rare ----
      if ((k0 + 63) > rowbase) {
        const int qg = rowbase + l15;
#pragma unroll
        for (int nt = 0; nt < 4; ++nt)
#pragma unroll
          for (int r = 0; r < 4; ++r)
            if (qg < (k0 + nt * 16 + quad * 4 + r)) accs[nt][r] = -1.0e30f;
      }

      // ---- row max: in-lane tree + 2 shfl ----
      float t0 = fmaxf(fmaxf(accs[0][0], accs[0][1]),
                       fmaxf(accs[0][2], accs[0][3]));
      float t1 = fmaxf(fmaxf(accs[1][0], accs[1][1]),
                       fmaxf(accs[1][2], accs[1][3]));
      float t2 = fmaxf(fmaxf(accs[2][0], accs[2][1]),
                       fmaxf(accs[2][2], accs[2][3]));
      float t3 = fmaxf(fmaxf(accs[3][0], accs[3][1]),
                       fmaxf(accs[3][2], accs[3][3]));
      float mx = fmaxf(fmaxf(t0, t1), fmaxf(t2, t3));
      mx = fmaxf(mx, __shfl_xor(mx, 16));
      mx = fmaxf(mx, __shfl_xor(mx, 32));

      // ---- defer-max (T13) ----
      const int defer = __all(mx <= m_s + 8.0f);
      float alv = 1.0f;
      if (!defer) {
        const float mnew = fmaxf(m_s, mx);
        alv = __expf(m_s - mnew);
        m_s = mnew;
      }

      // ---- exp ----
#pragma unroll
      for (int nt = 0; nt < 4; ++nt)
#pragma unroll
        for (int r = 0; r < 4; ++r)
          accs[nt][r] = __expf(accs[nt][r] - m_s);

      // ---- pack + write P early (ds latency overlaps the sum) ----
#pragma unroll
      for (int nt = 0; nt < 4; ++nt) {
        uint2 w;
        asm("v_cvt_pk_bf16_f32 %0, %1, %2"
            : "=v"(w.x) : "v"(accs[nt][0]), "v"(accs[nt][1]));
        asm("v_cvt_pk_bf16_f32 %0, %1, %2"
            : "=v"(w.y) : "v"(accs[nt][2]), "v"(accs[nt][3]));
        const int prow = pr0 + l15;
        const int c0 = nt * 16 + quad * 4;
        *(uint2*)&Pl[prow * 64 + (((c0 >> 3) ^ (prow & 7)) << 3) + (c0 & 7)] =
            w;
      }

      // ---- row sum + state update ----
      float s0 = (accs[0][0] + accs[0][1]) + (accs[0][2] + accs[0][3]);
      float s1 = (accs[1][0] + accs[1][1]) + (accs[1][2] + accs[1][3]);
      float s2 = (accs[2][0] + accs[2][1]) + (accs[2][2] + accs[2][3]);
      float s3 = (accs[3][0] + accs[3][1]) + (accs[3][2] + accs[3][3]);
      float rs = (s0 + s1) + (s2 + s3);
      rs += __shfl_xor(rs, 16);
      rs += __shfl_xor(rs, 32);
      l_s = l_s * alv + rs;

      // ---- O rescale (only when max grew; al redistributed to PV rows) ----
      if (!defer) {
#pragma unroll
        for (int r = 0; r < 4; ++r) {
          const float a4 = __shfl(alv, 4 * quad + r);
#pragma unroll
          for (int nt2 = 0; nt2 < 8; ++nt2) acc_o[nt2][r] *= a4;
        }
      }

      asm volatile("s_waitcnt lgkmcnt(0)" ::: "memory");
      __builtin_amdgcn_sched_barrier(0);

      // ---- PV: O[16q x 128d] += P[16x64] @ V[64x128] ----
      s16x8 pa[2];
#pragma unroll
      for (int ks = 0; ks < 2; ++ks) {
        const int row = pr0 + l15;
        const int g = ks * 4 + quad;
        pa[ks] = *(const s16x8*)&Pl[row * 64 + ((g ^ (row & 7)) << 3)];
      }
      __builtin_amdgcn_s_setprio(1);
#pragma unroll
      for (int ks = 0; ks < 2; ++ks) {
        const int g = ks * 4 + quad;
#pragma unroll
        for (int nt2 = 0; nt2 < 8; ++nt2) {
          const int row = nt2 * 16 + l15;
          const s16x8 vf =
              *(const s16x8*)&Vt[row * 64 + ((g ^ (row & 7)) << 3)];
          acc_o[nt2] = __builtin_amdgcn_mfma_f32_16x16x32_bf16(pa[ks], vf,
                                                               acc_o[nt2], 0,
                                                               0, 0);
        }
      }
      __builtin_amdgcn_s_setprio(0);
    }

    __syncthreads();  // drains vmcnt: buf^1 staged; all LDS reads retired
  }

  // ---- epilogue: normalize + store (linv redistributed to PV rows) ----
  const float inv = 1.0f / l_s;
#pragma unroll
  for (int r = 0; r < 4; ++r) {
    const float linv = __shfl(inv, 4 * quad + r);
    const size_t orow =
        ((size_t)(b * T_ + rowbase + quad * 4 + r) * H_ + h) * D_;
#pragma unroll
    for (int nt2 = 0; nt2 < 8; ++nt2)
      o[orow + nt2 * 16 + l15] = f2bf(acc_o[nt2][r] * linv);
  }
}

// Fallback: zero d_out (fp32) so an undersized workspace fails cleanly.
__global__ void zero_out_k(float* __restrict__ out, int n) {
  const int i = blockIdx.x * blockDim.x + threadIdx.x;
  if (i < n) out[i] = 0.0f;
}

// ---------------------------------------------------------------------------
extern "C" void kernel_launch(void* const* d_in, const int* in_sizes, int n_in,
                              void* d_out, int out_size, void* d_ws,
                              size_t ws_size, hipStream_t stream) {
  const void* x    = d_in[0];
  const void* cosT = d_in[1];
  const void* sinT = d_in[2];
  const void* Wq   = d_in[3];
  const void* Wk   = d_in[4];
  const void* Wv   = d_in[5];
  const void* Wo   = d_in[6];
  float* out = (float*)d_out;

  // Workspace (bf16 elems): qbuf QN | kbuf KN | vbufT KN | obuf QN |
  //   WqT 4194304 | WkT 1048576 | WvT 1048576 | WoT 4194304  = 60 MiB.
  const size_t QN = QN_;
  const size_t KN = KN_;
  const size_t WQT = (size_t)HID_ * (H_ * D_);     // 4194304
  const size_t WKT = (size_t)HID_ * (KVH_ * D_);   // 1048576
  const size_t need = (2 * QN + 2 * KN + 2 * WQT + 2 * WKT) * sizeof(u16);
  if (ws_size < need) {
    zero_out_k<<<(out_size + 255) / 256, 256, 0, stream>>>(out, out_size);
    return;
  }

  u16* qbuf  = (u16*)d_ws;
  u16* kbuf  = qbuf + QN;
  u16* vbufT = kbuf + KN;    // V^T: [b][kvh][d][t]
  u16* obuf  = vbufT + KN;
  u16* WqT   = obuf + QN;    // WqT|WkT|WvT contiguous => fused-QKV WT[3072][K]
  u16* WkT   = WqT + WQT;
  u16* WvT   = WkT + WKT;
  u16* WoT   = WvT + WKT;

  const int M = B_ * T_;  // 4096
  dim3 blk(256);

  // One-time weight transposes (W[K][N] -> WT[N][K] bf16).
  transp_k<<<dim3((H_ * D_) / 64, HID_ / 64), blk, 0, stream>>>(
      Wq, WqT, HID_, H_ * D_);
  transp_k<<<dim3((KVH_ * D_) / 64, HID_ / 64), blk, 0, stream>>>(
      Wk, WkT, HID_, KVH_ * D_);
  transp_k<<<dim3((KVH_ * D_) / 64, HID_ / 64), blk, 0, stream>>>(
      Wv, WvT, HID_, KVH_ * D_);
  transp_k<<<dim3(HID_ / 64, (H_ * D_) / 64), blk, 0, stream>>>(
      Wo, WoT, H_ * D_, HID_);

  // Fused QKV projection: N = 2048(Q) + 512(K) + 512(V^T), one GEMM.
  gemm_mfma<3><<<dim3(3072 / 128, M / 128), blk, 0, stream>>>(
      x, WqT, qbuf, M, 3072, HID_);

  // RoPE. Q additionally pre-scaled by 1/sqrt(D) (folds attn scale).
  const int totq = B_ * T_ * H_ * (D_ / 2);   // 4194304
  rope_bf<<<totq / 256, blk, 0, stream>>>(qbuf, cosT, sinT, H_, totq,
                                          0.08838834764831845f);
  const int totk = B_ * T_ * KVH_ * (D_ / 2); // 1048576
  rope_bf<<<totk / 256, blk, 0, stream>>>(kbuf, cosT, sinT, KVH_, totk, 1.0f);

  // MFMA flash attention v4 (swapped QK^T, lane-local softmax).
  attn_mfma<<<dim3(B_ * H_, 16), dim3(512), 0, stream>>>(
      qbuf, kbuf, vbufT, obuf);

  // Output projection (MFMA, fp32 out).
  gemm_mfma<0><<<dim3(HID_ / 128, M / 128), blk, 0, stream>>>(
      obuf, WoT, out, M, HID_, H_ * D_);
}

// Round 6
// 330.074 us; speedup vs baseline: 2.2908x; 1.0590x over previous
//
#include <hip/hip_runtime.h>
#include <hip/hip_bf16.h>

#define B_   2
#define T_   2048
#define HID_ 2048
#define H_   16
#define KVH_ 4
#define D_   128
#define GQ_  (H_ / KVH_)

#define QN_  8388608   // B*T*H*D
#define KN_  2097152   // B*T*KVH*D

typedef unsigned short u16;
typedef __attribute__((ext_vector_type(8))) unsigned short us8v;
typedef __attribute__((ext_vector_type(8))) short s16x8;   // MFMA A/B frag
typedef __attribute__((ext_vector_type(4))) float f32x4;   // MFMA C/D frag

__device__ __forceinline__ float bf2f(u16 u) {
  return __uint_as_float(((unsigned)u) << 16);
}
__device__ __forceinline__ u16 f2bf(float f) {
  unsigned x = __float_as_uint(f);
  return (u16)((x + 0x7fffu + ((x >> 16) & 1u)) >> 16);  // RNE
}

// global(16B per lane) -> LDS direct, wave-uniform dst base + lane*16.
__device__ __forceinline__ void gl2lds(const void* gp, void* lp) {
  __builtin_amdgcn_global_load_lds(
      (const __attribute__((address_space(1))) unsigned int*)gp,
      (__attribute__((address_space(3))) unsigned int*)lp, 16, 0, 0);
}

// ---------------------------------------------------------------------------
// On-device dtype probe (bf16 vs fp32), per tensor — R7-proven on this
// mixed-dtype input set. Wave-uniform, deterministic, graph-capture safe.
// ---------------------------------------------------------------------------
__device__ __forceinline__ void probe2(const void* A, const void* W, int tid,
                                       bool* abf, bool* wbf) {
  __shared__ int cA, zA, cW, zW;
  if (tid == 0) { cA = 0; zA = 0; cW = 0; zW = 0; }
  __syncthreads();
  const int i = 16384 + tid;
  {
    const u16 raw = ((const u16*)A)[i];
    const float v = bf2f(raw);
    const bool bad = !(fabsf(v) <= 1e6f) ||
                     (v != 0.0f && fabsf(v) < 1e-10f);
    if (bad) atomicAdd(&cA, 1);
    if (((tid & 1) == 0) && raw == 0) atomicAdd(&zA, 1);
  }
  {
    const u16 raw = ((const u16*)W)[i];
    const float v = bf2f(raw);
    const bool bad = !(fabsf(v) <= 1e6f) ||
                     (v != 0.0f && fabsf(v) < 1e-10f);
    if (bad) atomicAdd(&cW, 1);
    if (((tid & 1) == 0) && raw == 0) atomicAdd(&zW, 1);
  }
  __syncthreads();
  *abf = (cA < 8) && (zA < 100);
  *wbf = (cW < 8) && (zW < 100);
}

// ---------------------------------------------------------------------------
// One-time activation convert: x (fp32 OR bf16, probed) -> bf16, vectorized.
// 8 elems/thread; fp32 path uses v_cvt_pk_bf16_f32 (4 asm ops vs 48 RNE).
// ---------------------------------------------------------------------------
__global__ __launch_bounds__(256) void conv_bf16(const void* __restrict__ in,
                                                 u16* __restrict__ outb,
                                                 int total8) {
  const int tid = threadIdx.x;
  bool ibf, dummy;
  probe2(in, in, tid, &ibf, &dummy);
  const int idx = blockIdx.x * 256 + tid;
  if (idx >= total8) return;
  if (ibf) {
    *(us8v*)&outb[(size_t)idx * 8] = *(const us8v*)((const u16*)in +
                                                    (size_t)idx * 8);
  } else {
    const float4 f0 = *(const float4*)((const float*)in + (size_t)idx * 8);
    const float4 f1 = *(const float4*)((const float*)in + (size_t)idx * 8 + 4);
    uint4 w;
    asm("v_cvt_pk_bf16_f32 %0, %1, %2" : "=v"(w.x) : "v"(f0.x), "v"(f0.y));
    asm("v_cvt_pk_bf16_f32 %0, %1, %2" : "=v"(w.y) : "v"(f0.z), "v"(f0.w));
    asm("v_cvt_pk_bf16_f32 %0, %1, %2" : "=v"(w.z) : "v"(f1.x), "v"(f1.y));
    asm("v_cvt_pk_bf16_f32 %0, %1, %2" : "=v"(w.w) : "v"(f1.z), "v"(f1.w));
    *(uint4*)&outb[(size_t)idx * 8] = w;
  }
}

// ---------------------------------------------------------------------------
// Transpose W[K][N] (bf16 OR fp32, probed) -> WT[N][K] bf16. Runs once per
// weight; makes GEMM B-staging k-contiguous (required by MFMA B-fragment).
// ---------------------------------------------------------------------------
__global__ __launch_bounds__(256) void transp_k(const void* __restrict__ Wv_,
                                                u16* __restrict__ WT,
                                                int K, int N) {
  const int tid = threadIdx.x;
  bool wbf, dummy;
  probe2(Wv_, Wv_, tid, &wbf, &dummy);

  __shared__ float tile[64][65];
  const int kb = blockIdx.y * 64;
  const int nb = blockIdx.x * 64;

  for (int it = tid; it < 512; it += 256) {
    const int r = it >> 3;            // k-row 0..63
    const int g = it & 7;             // n-granule
    const size_t off = (size_t)(kb + r) * N + nb + g * 8;
    float f[8];
    if (wbf) {
      const us8v t8 = *(const us8v*)((const u16*)Wv_ + off);
#pragma unroll
      for (int e = 0; e < 8; ++e) f[e] = bf2f(t8[e]);
    } else {
      const float4 f0 = *(const float4*)((const float*)Wv_ + off);
      const float4 f1 = *(const float4*)((const float*)Wv_ + off + 4);
      f[0] = f0.x; f[1] = f0.y; f[2] = f0.z; f[3] = f0.w;
      f[4] = f1.x; f[5] = f1.y; f[6] = f1.z; f[7] = f1.w;
    }
#pragma unroll
    for (int e = 0; e < 8; ++e) tile[r][g * 8 + e] = f[e];
  }
  __syncthreads();
  for (int it = tid; it < 512; it += 256) {
    const int n = it >> 3;            // 0..63
    const int g = it & 7;             // k-granule
    us8v tmp;
#pragma unroll
    for (int e = 0; e < 8; ++e) tmp[e] = f2bf(tile[g * 8 + e][n]);
    *(us8v*)&WT[(size_t)(nb + n) * K + kb + g * 8] = tmp;
  }
}

// ---------------------------------------------------------------------------
// MFMA GEMM v2: C[M,N] = A[M,K] @ W[K,N]; A bf16 (pre-converted), W
// pre-transposed (WT[N][K] bf16). 128x128 tile, 4 waves (2x2), 4x4
// v_mfma_f32_16x16x32_bf16 per wave, BK=32.
// NEW: 2-PHASE DOUBLE-BUFFERED K-loop (T3-min): STAGE(t+1,buf^1) issues
// BEFORE compute(t); the single end-of-step barrier drains vmcnt ->
// staging latency hides under ds_read+MFMA (R5's 1-phase exposed it
// every step; grid gives only 2-3 blocks/CU so no implicit masking).
// LDS linear, granule XOR g^((r>>1)&3) folded into the global source
// (m173); fragment reads apply the same involution -> conflict-free.
// OMODE: 0 = fp32 out row-major.
//        3 = fused QKV epilogue: col<2048 -> qbuf; col<2560 -> kbuf;
//            else -> vT[((b*KVH+kvh)*D+d)*T+t] (V^T for attention PV).
// ---------------------------------------------------------------------------
#define G_STAGE(bi, kk)                                                       \
  do {                                                                        \
    _Pragma("unroll") for (int _p = 0; _p < 2; ++_p) {                        \
      const int _it = tid + _p * 256;                                         \
      const int _r = _it >> 2, _g = _it & 3;                                  \
      const int _gs = _g ^ ((_r >> 1) & 3);                                   \
      gl2lds(Ab + (size_t)(m0 + _r) * K + (kk) + _gs * 8,                     \
             &Alds[bi][((tid & ~63) + _p * 256) * 8]);                        \
    }                                                                         \
    _Pragma("unroll") for (int _p = 0; _p < 2; ++_p) {                        \
      const int _it = tid + _p * 256;                                         \
      const int _n = _it >> 2, _g = _it & 3;                                  \
      const int _gs = _g ^ ((_n >> 1) & 3);                                   \
      gl2lds(WT + (size_t)(n0 + _n) * K + (kk) + _gs * 8,                     \
             &Blds[bi][((tid & ~63) + _p * 256) * 8]);                        \
    }                                                                         \
  } while (0)

template <int OMODE>
__global__ __launch_bounds__(256) void gemm_mfma(const u16* __restrict__ Ab,
                                                 const u16* __restrict__ WT,
                                                 void* __restrict__ Cv,
                                                 int M, int N, int K) {
  const int tid = threadIdx.x;

  __shared__ __align__(16) u16 Alds[2][128 * 32];
  __shared__ __align__(16) u16 Blds[2][128 * 32];

  const int m0 = blockIdx.y * 128;
  const int n0 = blockIdx.x * 128;
  const int wave = tid >> 6;
  const int lane = tid & 63;
  const int wm = (wave >> 1) * 64;
  const int wn = (wave & 1) * 64;
  const int lrow = lane & 15;
  const int lq = lane >> 4;

  f32x4 acc[4][4] = {};

  G_STAGE(0, 0);
  __syncthreads();  // drains vmcnt: buf0 ready

  int cur = 0;
  for (int k0 = 0; k0 < K; k0 += 32) {
    if (k0 + 32 < K) G_STAGE(cur ^ 1, k0 + 32);  // prefetch next step

    s16x8 af[4], bfr[4];
#pragma unroll
    for (int mi = 0; mi < 4; ++mi) {
      const int row = wm + 16 * mi + lrow;
      af[mi] =
          *(const s16x8*)&Alds[cur][row * 32 + ((lq ^ ((row >> 1) & 3)) * 8)];
    }
#pragma unroll
    for (int ni = 0; ni < 4; ++ni) {
      const int row = wn + 16 * ni + lrow;
      bfr[ni] =
          *(const s16x8*)&Blds[cur][row * 32 + ((lq ^ ((row >> 1) & 3)) * 8)];
    }
    __builtin_amdgcn_s_setprio(1);
#pragma unroll
    for (int mi = 0; mi < 4; ++mi)
#pragma unroll
      for (int ni = 0; ni < 4; ++ni)
        acc[mi][ni] = __builtin_amdgcn_mfma_f32_16x16x32_bf16(
            af[mi], bfr[ni], acc[mi][ni], 0, 0, 0);
    __builtin_amdgcn_s_setprio(0);

    __syncthreads();  // drains vmcnt: buf^1 staged; buf[cur] reads retired
    cur ^= 1;
  }

  // epilogue: D col=lane&15, row=quad*4+reg
#pragma unroll
  for (int mi = 0; mi < 4; ++mi) {
#pragma unroll
    for (int ni = 0; ni < 4; ++ni) {
      const int row0 = m0 + wm + 16 * mi + lq * 4;
      const int col = n0 + wn + 16 * ni + lrow;
#pragma unroll
      for (int r = 0; r < 4; ++r) {
        const int row = row0 + r;
        if (OMODE == 0) {
          ((float*)Cv)[(size_t)row * N + col] = acc[mi][ni][r];
        } else {
          const u16 val = f2bf(acc[mi][ni][r]);
          if (col < 2048) {
            ((u16*)Cv)[(size_t)row * 2048 + col] = val;           // qbuf
          } else if (col < 2560) {
            ((u16*)Cv)[QN_ + (size_t)row * 512 + (col - 2048)] = val;  // kbuf
          } else {
            const int c = col - 2560;          // 0..511
            const int kvh = c >> 7;
            const int d = c & 127;
            const int bb = row >> 11;          // T_ == 2048
            const int tt = row & (T_ - 1);
            ((u16*)Cv)[QN_ + KN_ +
                       ((size_t)(bb * KVH_ + kvh) * D_ + d) * T_ + tt] = val;
          }
        }
      }
    }
  }
}

// ---------------------------------------------------------------------------
// RoPE (rotate-half), in place on a BF16 (B, T, NH, D) workspace tensor.
// qs: output scale (1/sqrt(D) for Q — folds the attention scale into Q).
// ---------------------------------------------------------------------------
__global__ __launch_bounds__(256) void rope_bf(u16* __restrict__ t,
                                               const void* __restrict__ cosT,
                                               const void* __restrict__ sinT,
                                               int NH, int total, float qs) {
  const int tid = threadIdx.x;
  bool cbf, sbf;
  probe2(cosT, sinT, tid, &cbf, &sbf);

  const int idx = blockIdx.x * blockDim.x + tid;
  if (idx >= total) return;
  const int d = idx & 63;
  const int rest = idx >> 6;
  const int tt = (rest / NH) % T_;
  const size_t base = (size_t)rest * D_;
  const int ci = tt * D_ + d;
  float c1, s1, c2, s2;
  if (cbf) {
    c1 = bf2f(((const u16*)cosT)[ci]);
    c2 = bf2f(((const u16*)cosT)[ci + 64]);
  } else {
    c1 = ((const float*)cosT)[ci];
    c2 = ((const float*)cosT)[ci + 64];
  }
  if (sbf) {
    s1 = bf2f(((const u16*)sinT)[ci]);
    s2 = bf2f(((const u16*)sinT)[ci + 64]);
  } else {
    s1 = ((const float*)sinT)[ci];
    s2 = ((const float*)sinT)[ci + 64];
  }
  const float x1 = bf2f(t[base + d]);
  const float x2 = bf2f(t[base + d + 64]);
  t[base + d] = f2bf((x1 * c1 - x2 * s1) * qs);
  t[base + d + 64] = f2bf((x2 * c2 + x1 * s2) * qs);
}

// ---------------------------------------------------------------------------
// Causal GQA flash attention, MFMA v4 (unchanged from R5, passing):
// swapped QK^T (lane-local softmax), paired q-tiles, 8 waves, dbuf
// global_load_lds staging, defer-max, setprio.
// ---------------------------------------------------------------------------
#define ATT_STAGE(bi, ktile)                                                  \
  do {                                                                        \
    const int _k0 = (ktile) * 64;                                             \
    u16* _bk = &SM[(bi) * 16384];                                             \
    _Pragma("unroll") for (int _p = 0; _p < 2; ++_p) {                        \
      const int _it = tid + _p * 512;                                         \
      const int _r = _it >> 4, _s = _it & 15;                                 \
      gl2lds(kp + (size_t)(_k0 + _r) * (KVH_ * D_) + ((_s ^ (_r & 7)) * 8),   \
             &_bk[((tid & ~63) + _p * 512) * 8]);                             \
    }                                                                         \
    _Pragma("unroll") for (int _p = 0; _p < 2; ++_p) {                        \
      const int _it = tid + _p * 512;                                         \
      const int _r = _it >> 3, _s = _it & 7;                                  \
      gl2lds(vp + (size_t)_r * T_ + _k0 + ((_s ^ (_r & 7)) * 8),              \
             &_bk[8192 + ((tid & ~63) + _p * 512) * 8]);                      \
    }                                                                         \
  } while (0)

__global__ __launch_bounds__(512, 4) void attn_mfma(
    const u16* __restrict__ q, const u16* __restrict__ k,
    const u16* __restrict__ vT, u16* __restrict__ o) {
  const int tid = threadIdx.x;
  const int ip = blockIdx.y;                 // pair index 0..15
  const int bh = blockIdx.x;
  const int b = bh >> 4;
  const int h = bh & 15;
  const int kvh = h >> 2;
  const int hi0 = 64 * (31 - ip);
  const int lo0 = 64 * ip;

  __shared__ __align__(16) u16 SM[2 * 16384];  // dbuf {Ks 64x128, Vt 128x64}
  __shared__ __align__(16) u16 Pl[128 * 64];   // P (bf16), granule-XOR

  const int wave = tid >> 6;                 // 0..7
  const int lane = tid & 63;
  const int l15 = lane & 15;
  const int quad = lane >> 4;
  const bool isHi = wave < 4;
  const int rowbase = isHi ? (hi0 + 16 * wave) : (lo0 + 16 * (wave - 4));
  const int pr0 = 16 * wave;                 // Pl row base, wave-private

  const u16* kp = k + ((size_t)b * T_ * KVH_ + kvh) * D_;
  const u16* vp = vT + (size_t)(b * KVH_ + kvh) * D_ * T_;

  // Q fragment, reg-resident: B-layout [n=q=l15][d=st*32+quad*8+j].
  s16x8 qf[4];
  {
    const size_t qrow = ((size_t)(b * T_ + rowbase + l15) * H_ + h) * D_;
#pragma unroll
    for (int st = 0; st < 4; ++st)
      qf[st] = *(const s16x8*)&q[qrow + st * 32 + quad * 8];
  }

  f32x4 acc_o[8] = {};   // PV out: row q=quad*4+r, col d=nt2*16+l15
  float m_s = -1.0e30f, l_s = 0.0f;   // per-lane state for q = rowbase+l15

  const int nkt = 32 - ip;  // hi tile count; lo active while kt <= ip

  ATT_STAGE(0, 0);
  __syncthreads();

  for (int kt = 0; kt < nkt; ++kt) {
    const int k0 = kt * 64;
    const u16* Ks = &SM[(kt & 1) * 16384];
    const u16* Vt = Ks + 8192;

    if (kt + 1 < nkt) ATT_STAGE((kt + 1) & 1, kt + 1);

    const bool active = isHi || (kt <= ip);  // wave-uniform
    if (active) {
      // ---- swapped QK^T: lane holds S[q=l15][k=nt*16+quad*4+r] ----
      f32x4 accs[4] = {};
      __builtin_amdgcn_s_setprio(1);
#pragma unroll
      for (int st = 0; st < 4; ++st) {
        const int g = st * 4 + quad;
#pragma unroll
        for (int nt = 0; nt < 4; ++nt) {
          const int row = nt * 16 + l15;
          const s16x8 kf =
              *(const s16x8*)&Ks[row * 128 + ((g ^ (row & 7)) << 3)];
          accs[nt] = __builtin_amdgcn_mfma_f32_16x16x32_bf16(kf, qf[st],
                                                             accs[nt], 0, 0,
                                                             0);
        }
      }
      __builtin_amdgcn_s_setprio(0);

      // ---- causal mask: wave-uniform branch, rare ----
      if ((k0 + 63) > rowbase) {
        const int qg = rowbase + l15;
#pragma unroll
        for (int nt = 0; nt < 4; ++nt)
#pragma unroll
          for (int r = 0; r < 4; ++r)
            if (qg < (k0 + nt * 16 + quad * 4 + r)) accs[nt][r] = -1.0e30f;
      }

      // ---- row max: in-lane tree + 2 shfl ----
      float t0 = fmaxf(fmaxf(accs[0][0], accs[0][1]),
                       fmaxf(accs[0][2], accs[0][3]));
      float t1 = fmaxf(fmaxf(accs[1][0], accs[1][1]),
                       fmaxf(accs[1][2], accs[1][3]));
      float t2 = fmaxf(fmaxf(accs[2][0], accs[2][1]),
                       fmaxf(accs[2][2], accs[2][3]));
      float t3 = fmaxf(fmaxf(accs[3][0], accs[3][1]),
                       fmaxf(accs[3][2], accs[3][3]));
      float mx = fmaxf(fmaxf(t0, t1), fmaxf(t2, t3));
      mx = fmaxf(mx, __shfl_xor(mx, 16));
      mx = fmaxf(mx, __shfl_xor(mx, 32));

      // ---- defer-max (T13) ----
      const int defer = __all(mx <= m_s + 8.0f);
      float alv = 1.0f;
      if (!defer) {
        const float mnew = fmaxf(m_s, mx);
        alv = __expf(m_s - mnew);
        m_s = mnew;
      }

      // ---- exp ----
#pragma unroll
      for (int nt = 0; nt < 4; ++nt)
#pragma unroll
        for (int r = 0; r < 4; ++r)
          accs[nt][r] = __expf(accs[nt][r] - m_s);

      // ---- pack + write P early (ds latency overlaps the sum) ----
#pragma unroll
      for (int nt = 0; nt < 4; ++nt) {
        uint2 w;
        asm("v_cvt_pk_bf16_f32 %0, %1, %2"
            : "=v"(w.x) : "v"(accs[nt][0]), "v"(accs[nt][1]));
        asm("v_cvt_pk_bf16_f32 %0, %1, %2"
            : "=v"(w.y) : "v"(accs[nt][2]), "v"(accs[nt][3]));
        const int prow = pr0 + l15;
        const int c0 = nt * 16 + quad * 4;
        *(uint2*)&Pl[prow * 64 + (((c0 >> 3) ^ (prow & 7)) << 3) + (c0 & 7)] =
            w;
      }

      // ---- row sum + state update ----
      float s0 = (accs[0][0] + accs[0][1]) + (accs[0][2] + accs[0][3]);
      float s1 = (accs[1][0] + accs[1][1]) + (accs[1][2] + accs[1][3]);
      float s2 = (accs[2][0] + accs[2][1]) + (accs[2][2] + accs[2][3]);
      float s3 = (accs[3][0] + accs[3][1]) + (accs[3][2] + accs[3][3]);
      float rs = (s0 + s1) + (s2 + s3);
      rs += __shfl_xor(rs, 16);
      rs += __shfl_xor(rs, 32);
      l_s = l_s * alv + rs;

      // ---- O rescale (only when max grew; al redistributed to PV rows) ----
      if (!defer) {
#pragma unroll
        for (int r = 0; r < 4; ++r) {
          const float a4 = __shfl(alv, 4 * quad + r);
#pragma unroll
          for (int nt2 = 0; nt2 < 8; ++nt2) acc_o[nt2][r] *= a4;
        }
      }

      asm volatile("s_waitcnt lgkmcnt(0)" ::: "memory");
      __builtin_amdgcn_sched_barrier(0);

      // ---- PV: O[16q x 128d] += P[16x64] @ V[64x128] ----
      s16x8 pa[2];
#pragma unroll
      for (int ks = 0; ks < 2; ++ks) {
        const int row = pr0 + l15;
        const int g = ks * 4 + quad;
        pa[ks] = *(const s16x8*)&Pl[row * 64 + ((g ^ (row & 7)) << 3)];
      }
      __builtin_amdgcn_s_setprio(1);
#pragma unroll
      for (int ks = 0; ks < 2; ++ks) {
        const int g = ks * 4 + quad;
#pragma unroll
        for (int nt2 = 0; nt2 < 8; ++nt2) {
          const int row = nt2 * 16 + l15;
          const s16x8 vf =
              *(const s16x8*)&Vt[row * 64 + ((g ^ (row & 7)) << 3)];
          acc_o[nt2] = __builtin_amdgcn_mfma_f32_16x16x32_bf16(pa[ks], vf,
                                                               acc_o[nt2], 0,
                                                               0, 0);
        }
      }
      __builtin_amdgcn_s_setprio(0);
    }

    __syncthreads();  // drains vmcnt: buf^1 staged; all LDS reads retired
  }

  // ---- epilogue: normalize + store (linv redistributed to PV rows) ----
  const float inv = 1.0f / l_s;
#pragma unroll
  for (int r = 0; r < 4; ++r) {
    const float linv = __shfl(inv, 4 * quad + r);
    const size_t orow =
        ((size_t)(b * T_ + rowbase + quad * 4 + r) * H_ + h) * D_;
#pragma unroll
    for (int nt2 = 0; nt2 < 8; ++nt2)
      o[orow + nt2 * 16 + l15] = f2bf(acc_o[nt2][r] * linv);
  }
}

// Fallback: zero d_out (fp32) so an undersized workspace fails cleanly.
__global__ void zero_out_k(float* __restrict__ out, int n) {
  const int i = blockIdx.x * blockDim.x + threadIdx.x;
  if (i < n) out[i] = 0.0f;
}

// ---------------------------------------------------------------------------
extern "C" void kernel_launch(void* const* d_in, const int* in_sizes, int n_in,
                              void* d_out, int out_size, void* d_ws,
                              size_t ws_size, hipStream_t stream) {
  const void* x    = d_in[0];
  const void* cosT = d_in[1];
  const void* sinT = d_in[2];
  const void* Wq   = d_in[3];
  const void* Wk   = d_in[4];
  const void* Wv   = d_in[5];
  const void* Wo   = d_in[6];
  float* out = (float*)d_out;

  // Workspace (bf16 elems): qbuf QN | kbuf KN | vbufT KN | obuf QN |
  //   WqT 4194304 | WkT 1048576 | WvT 1048576 | WoT 4194304  = 60 MiB.
  // xb (bf16 copy of x, QN elems) ALIASES obuf: x is consumed by the QKV
  // GEMM, which completes before attention writes obuf (stream-ordered).
  const size_t QN = QN_;
  const size_t KN = KN_;
  const size_t WQT = (size_t)HID_ * (H_ * D_);     // 4194304
  const size_t WKT = (size_t)HID_ * (KVH_ * D_);   // 1048576
  const size_t need = (2 * QN + 2 * KN + 2 * WQT + 2 * WKT) * sizeof(u16);
  if (ws_size < need) {
    zero_out_k<<<(out_size + 255) / 256, 256, 0, stream>>>(out, out_size);
    return;
  }

  u16* qbuf  = (u16*)d_ws;
  u16* kbuf  = qbuf + QN;
  u16* vbufT = kbuf + KN;    // V^T: [b][kvh][d][t]
  u16* obuf  = vbufT + KN;
  u16* xb    = obuf;         // alias (see above)
  u16* WqT   = obuf + QN;    // WqT|WkT|WvT contiguous => fused-QKV WT[3072][K]
  u16* WkT   = WqT + WQT;
  u16* WvT   = WkT + WKT;
  u16* WoT   = WvT + WKT;

  const int M = B_ * T_;  // 4096
  dim3 blk(256);

  // One-time weight transposes (W[K][N] -> WT[N][K] bf16).
  transp_k<<<dim3((H_ * D_) / 64, HID_ / 64), blk, 0, stream>>>(
      Wq, WqT, HID_, H_ * D_);
  transp_k<<<dim3((KVH_ * D_) / 64, HID_ / 64), blk, 0, stream>>>(
      Wk, WkT, HID_, KVH_ * D_);
  transp_k<<<dim3((KVH_ * D_) / 64, HID_ / 64), blk, 0, stream>>>(
      Wv, WvT, HID_, KVH_ * D_);
  transp_k<<<dim3(HID_ / 64, (H_ * D_) / 64), blk, 0, stream>>>(
      Wo, WoT, H_ * D_, HID_);

  // Activation convert: x -> bf16 (xb), one pass.
  conv_bf16<<<(int)(QN / 8 / 256), blk, 0, stream>>>(x, xb, (int)(QN / 8));

  // Fused QKV projection: N = 2048(Q) + 512(K) + 512(V^T), one GEMM.
  gemm_mfma<3><<<dim3(3072 / 128, M / 128), blk, 0, stream>>>(
      xb, WqT, qbuf, M, 3072, HID_);

  // RoPE. Q additionally pre-scaled by 1/sqrt(D) (folds attn scale).
  const int totq = B_ * T_ * H_ * (D_ / 2);   // 4194304
  rope_bf<<<totq / 256, blk, 0, stream>>>(qbuf, cosT, sinT, H_, totq,
                                          0.08838834764831845f);
  const int totk = B_ * T_ * KVH_ * (D_ / 2); // 1048576
  rope_bf<<<totk / 256, blk, 0, stream>>>(kbuf, cosT, sinT, KVH_, totk, 1.0f);

  // MFMA flash attention v4 (swapped QK^T, lane-local softmax).
  attn_mfma<<<dim3(B_ * H_, 16), dim3(512), 0, stream>>>(
      qbuf, kbuf, vbufT, obuf);

  // Output projection (MFMA, fp32 out).
  gemm_mfma<0><<<dim3(HID_ / 128, M / 128), blk, 0, stream>>>(
      obuf, WoT, out, M, HID_, H_ * D_);
}